// Round 1
// baseline (1017.205 us; speedup 1.0000x reference)
//
#include <hip/hip_runtime.h>
#include <math.h>

// Problem constants (fixed by setup_inputs)
#define BB 8
#define NN 1024
#define CC 768
#define HH 12
#define DH 64
#define QKV3 2304   // 3*C

// ---------------------------------------------------------------------------
// K1/K4: fp32 tiled GEMM: C[M,N] = A[M,K] @ B[N,K]^T + bias[N]
// 64x64 tile, BK=16, 256 threads, 4x4 per thread.
// ---------------------------------------------------------------------------
__global__ __launch_bounds__(256)
void gemm_abt(const float* __restrict__ A, const float* __restrict__ B,
              const float* __restrict__ bias, float* __restrict__ C,
              int M, int N, int K) {
  __shared__ float As[16][68];  // [k][m], stride 68 keeps float4 rows 16B-aligned
  __shared__ float Bs[16][68];  // [k][n]
  const int tid = threadIdx.x;
  const int tx = tid & 15, ty = tid >> 4;
  const int row0 = blockIdx.y * 64;
  const int col0 = blockIdx.x * 64;
  const int lr = tid >> 2;          // 0..63
  const int lk = (tid & 3) << 2;    // 0,4,8,12

  float acc[4][4] = {};
  for (int kt = 0; kt < K; kt += 16) {
    float4 a = *(const float4*)(A + (size_t)(row0 + lr) * K + kt + lk);
    float4 b = *(const float4*)(B + (size_t)(col0 + lr) * K + kt + lk);
    As[lk+0][lr] = a.x; As[lk+1][lr] = a.y; As[lk+2][lr] = a.z; As[lk+3][lr] = a.w;
    Bs[lk+0][lr] = b.x; Bs[lk+1][lr] = b.y; Bs[lk+2][lr] = b.z; Bs[lk+3][lr] = b.w;
    __syncthreads();
#pragma unroll
    for (int kk = 0; kk < 16; ++kk) {
      float4 av = *(const float4*)(&As[kk][ty << 2]);
      float4 bv = *(const float4*)(&Bs[kk][tx << 2]);
      float am[4] = {av.x, av.y, av.z, av.w};
      float bn[4] = {bv.x, bv.y, bv.z, bv.w};
#pragma unroll
      for (int i = 0; i < 4; ++i)
#pragma unroll
        for (int j = 0; j < 4; ++j)
          acc[i][j] = fmaf(am[i], bn[j], acc[i][j]);
    }
    __syncthreads();
  }
#pragma unroll
  for (int i = 0; i < 4; ++i) {
    int m = row0 + (ty << 2) + i;
    int n = col0 + (tx << 2);
    float4 c;
    c.x = acc[i][0] + bias[n + 0];
    c.y = acc[i][1] + bias[n + 1];
    c.z = acc[i][2] + bias[n + 2];
    c.w = acc[i][3] + bias[n + 3];
    *(float4*)(C + (size_t)m * N + n) = c;
  }
}

// ---------------------------------------------------------------------------
// K2: RoPE2D on q/k image-token prefix + split QKV[8192,2304] into
// q,k,v each [B,H,N,Dh]. One block per (b,n), 256 threads, 9 elems each.
// ---------------------------------------------------------------------------
__global__ __launch_bounds__(256)
void rope_split(const float* __restrict__ qkv, const int* __restrict__ pos2d,
                float* __restrict__ q, float* __restrict__ k, float* __restrict__ v,
                int num_img) {
  const int n = blockIdx.x;
  const int b = blockIdx.y;
  const float* base = qkv + (size_t)(b * NN + n) * QKV3;
  const bool img = (n < num_img);
  float py = 0.f, px = 0.f;
  if (img) {
    py = (float)pos2d[(b * num_img + n) * 2 + 0];
    px = (float)pos2d[(b * num_img + n) * 2 + 1];
  }
  for (int e = threadIdx.x; e < QKV3; e += 256) {
    int s   = e / CC;          // 0=q,1=k,2=v
    int rem = e - s * CC;
    int h   = rem >> 6;
    int d   = rem & 63;
    float t = base[e];
    float outv;
    if (s < 2 && img) {
      // Dh=64 split into y half (d<32) and x half (d>=32); each half is a
      // D=32 rope1d with pairs (j, j+16), inv_freq[i]=100^(-i/16).
      int half = d >> 5;
      int j    = d & 31;
      int i16  = j & 15;
      float pos = half ? px : py;
      float inv = powf(100.0f, -(float)i16 * (1.0f / 16.0f));
      float ang = pos * inv;
      float sn, cs;
      sincosf(ang, &sn, &cs);
      int pd = (j < 16) ? d + 16 : d - 16;
      float t2 = base[s * CC + h * 64 + pd];
      float rot = (j < 16) ? -t2 : t2;
      outv = t * cs + rot * sn;
    } else {
      outv = t;
    }
    float* dst = (s == 0) ? q : (s == 1) ? k : v;
    dst[((size_t)(b * HH + h) * NN + n) * DH + d] = outv;
  }
}

// ---------------------------------------------------------------------------
// K3: fp32 flash attention. Grid (16 q-tiles, 96 bh). 256 threads.
// Q tile 64 rows; loop 16 K/V tiles of 64; online softmax; O in regs.
// LDS: Qs (transposed [d][row]), KP (K transposed, aliased as P after S),
// Vs ([kk][d]). 3*64*68*4 = 52,224 B.
// ---------------------------------------------------------------------------
__global__ __launch_bounds__(256)
void attn_fp32(const float* __restrict__ Q, const float* __restrict__ K,
               const float* __restrict__ V, float* __restrict__ O) {
  __shared__ float Qs[64][68];  // [d][qrow]
  __shared__ float KP[64][68];  // phase 1: [d][kcol]; phase 2: P^T [kcol][qrow]
  __shared__ float Vs[64][68];  // [kk][d]

  const int tid = threadIdx.x;
  const int tx = tid & 15, ty = tid >> 4;
  const int r0 = ty << 2;   // q rows owned
  const int c0 = tx << 2;   // s cols / v dims owned
  const int qt = blockIdx.x;      // 0..15
  const int bh = blockIdx.y;      // 0..95

  const float* qbase = Q + ((size_t)bh * NN + qt * 64) * DH;
  const float* kbase = K + (size_t)bh * NN * DH;
  const float* vbase = V + (size_t)bh * NN * DH;

  // load Q tile transposed: 1024 float4s, 4 per thread
  for (int t = tid; t < 64 * 16; t += 256) {
    int row = t >> 4;
    int d4  = (t & 15) << 2;
    float4 a = *(const float4*)(qbase + row * DH + d4);
    Qs[d4+0][row] = a.x; Qs[d4+1][row] = a.y; Qs[d4+2][row] = a.z; Qs[d4+3][row] = a.w;
  }

  float m_i[4], l_i[4], o[4][4];
#pragma unroll
  for (int i = 0; i < 4; ++i) {
    m_i[i] = -1e30f; l_i[i] = 0.f;
#pragma unroll
    for (int j = 0; j < 4; ++j) o[i][j] = 0.f;
  }
  const float scale = 0.125f;  // 64^-0.5

  for (int kt = 0; kt < NN; kt += 64) {
    __syncthreads();  // prev-iter P/V reads done (also covers Qs on iter 0)
    for (int t = tid; t < 64 * 16; t += 256) {
      int row = t >> 4;
      int d4  = (t & 15) << 2;
      float4 a = *(const float4*)(kbase + (size_t)(kt + row) * DH + d4);
      KP[d4+0][row] = a.x; KP[d4+1][row] = a.y; KP[d4+2][row] = a.z; KP[d4+3][row] = a.w;
      float4 bv = *(const float4*)(vbase + (size_t)(kt + row) * DH + d4);
      *(float4*)(&Vs[row][d4]) = bv;
    }
    __syncthreads();

    // S = Q K^T (scaled)
    float s[4][4] = {};
#pragma unroll
    for (int d = 0; d < 64; ++d) {
      float4 qv = *(const float4*)(&Qs[d][r0]);
      float4 kv = *(const float4*)(&KP[d][c0]);
      float qa[4] = {qv.x, qv.y, qv.z, qv.w};
      float kb[4] = {kv.x, kv.y, kv.z, kv.w};
#pragma unroll
      for (int i = 0; i < 4; ++i)
#pragma unroll
        for (int j = 0; j < 4; ++j)
          s[i][j] = fmaf(qa[i], kb[j], s[i][j]);
    }
    __syncthreads();  // everyone done reading K before P overwrites KP

    // online softmax across the 16 tx lanes sharing each row group
    float p[4][4];
#pragma unroll
    for (int i = 0; i < 4; ++i) {
      float rmax = fmaxf(fmaxf(s[i][0], s[i][1]), fmaxf(s[i][2], s[i][3])) * scale;
#pragma unroll
      for (int off = 1; off < 16; off <<= 1)
        rmax = fmaxf(rmax, __shfl_xor(rmax, off, 64));
      float m_new = fmaxf(m_i[i], rmax);
      float alpha = __expf(m_i[i] - m_new);
      float rsum = 0.f;
#pragma unroll
      for (int j = 0; j < 4; ++j) {
        p[i][j] = __expf(s[i][j] * scale - m_new);
        rsum += p[i][j];
      }
#pragma unroll
      for (int off = 1; off < 16; off <<= 1)
        rsum += __shfl_xor(rsum, off, 64);
      l_i[i] = l_i[i] * alpha + rsum;
      m_i[i] = m_new;
#pragma unroll
      for (int j = 0; j < 4; ++j) o[i][j] *= alpha;
#pragma unroll
      for (int j = 0; j < 4; ++j) KP[c0 + j][r0 + i] = p[i][j];  // P^T
    }
    __syncthreads();  // P visible

    // O += P @ V
#pragma unroll
    for (int kk = 0; kk < 64; ++kk) {
      float4 pv = *(const float4*)(&KP[kk][r0]);
      float4 vv = *(const float4*)(&Vs[kk][c0]);
      float pa[4] = {pv.x, pv.y, pv.z, pv.w};
      float vb[4] = {vv.x, vv.y, vv.z, vv.w};
#pragma unroll
      for (int i = 0; i < 4; ++i)
#pragma unroll
        for (int j = 0; j < 4; ++j)
          o[i][j] = fmaf(pa[i], vb[j], o[i][j]);
    }
  }

  // epilogue: normalize and write to [B,N,C] (n-major so proj GEMM is row-major)
  const int b = bh / HH;
  const int h = bh % HH;
#pragma unroll
  for (int i = 0; i < 4; ++i) {
    int n = qt * 64 + r0 + i;
    float inv_l = 1.0f / l_i[i];
    float4 val;
    val.x = o[i][0] * inv_l;
    val.y = o[i][1] * inv_l;
    val.z = o[i][2] * inv_l;
    val.w = o[i][3] * inv_l;
    *(float4*)(O + (size_t)(b * NN + n) * CC + h * DH + c0) = val;
  }
}

// ---------------------------------------------------------------------------
extern "C" void kernel_launch(void* const* d_in, const int* in_sizes, int n_in,
                              void* d_out, int out_size, void* d_ws, size_t ws_size,
                              hipStream_t stream) {
  const float* x      = (const float*)d_in[0];   // [8,1024,768]
  const float* qkv_w  = (const float*)d_in[1];   // [2304,768]
  const float* qkv_b  = (const float*)d_in[2];   // [2304]
  const float* proj_w = (const float*)d_in[3];   // [768,768]
  const float* proj_b = (const float*)d_in[4];   // [768]
  const int*   pos2d  = (const int*)d_in[5];     // [8,num_img,2]
  const int num_img = in_sizes[5] / (2 * BB);    // 784 (host-side, capture-safe)

  float* ws  = (float*)d_ws;
  float* qkv = ws;                               // 8192*2304   = 18,874,368 f
  float* q   = ws + 18874368;                    // 6,291,456 f each
  float* k   = ws + 25165824;
  float* v   = ws + 31457280;
  float* ao  = ws + 37748736;                    // attn out [8192,768]
  float* out = (float*)d_out;

  // K1: QKV = X @ Wqkv^T + b
  gemm_abt<<<dim3(QKV3 / 64, (BB * NN) / 64), 256, 0, stream>>>(
      x, qkv_w, qkv_b, qkv, BB * NN, QKV3, CC);

  // K2: RoPE2D + split/transpose to [B,H,N,Dh]
  rope_split<<<dim3(NN, BB), 256, 0, stream>>>(qkv, pos2d, q, k, v, num_img);

  // K3: flash attention fp32
  attn_fp32<<<dim3(NN / 64, BB * HH), 256, 0, stream>>>(q, k, v, ao);

  // K4: out = AO @ Wproj^T + b
  gemm_abt<<<dim3(CC / 64, (BB * NN) / 64), 256, 0, stream>>>(
      ao, proj_w, proj_b, out, BB * NN, CC, CC);
}

// Round 2
// 382.981 us; speedup vs baseline: 2.6560x; 2.6560x over previous
//
#include <hip/hip_runtime.h>
#include <math.h>

typedef _Float16 F16;
typedef _Float16 f16x8 __attribute__((ext_vector_type(8)));
typedef _Float16 f16x4 __attribute__((ext_vector_type(4)));
typedef float f32x4 __attribute__((ext_vector_type(4)));

#define BB 8
#define NN 1024
#define CC 768
#define HH 12
#define DH 64
#define QKV3 2304

// ---------------------------------------------------------------------------
// Split fp32 -> fp16 hi + fp16 lo (residual). n4 = count of float4 groups.
// ---------------------------------------------------------------------------
__global__ __launch_bounds__(256)
void split_f32(const float* __restrict__ src, F16* __restrict__ hi,
               F16* __restrict__ lo, int n4) {
  int i = blockIdx.x * 256 + threadIdx.x;
  if (i >= n4) return;
  float4 v = ((const float4*)src)[i];
  float a[4] = {v.x, v.y, v.z, v.w};
  f16x4 h, l;
#pragma unroll
  for (int j = 0; j < 4; ++j) {
    h[j] = (F16)a[j];
    l[j] = (F16)(a[j] - (float)h[j]);
  }
  ((f16x4*)hi)[i] = h;
  ((f16x4*)lo)[i] = l;
}

// ---------------------------------------------------------------------------
// Split-fp16 MFMA GEMM: C[M,N] = (Ahi+Alo)[M,K] @ (Bhi+Blo)[N,K]^T + bias[N]
// 3-term: Ah*Bh + Al*Bh + Ah*Bl (drop lo*lo). 128x128 tile, BK=32, 4 waves.
// ---------------------------------------------------------------------------
__global__ __launch_bounds__(256)
void gemm_split(const F16* __restrict__ Ahi, const F16* __restrict__ Alo,
                const F16* __restrict__ Bhi, const F16* __restrict__ Blo,
                const float* __restrict__ bias, float* __restrict__ C,
                int M, int N, int K) {
  __shared__ F16 Ash[2][128][40];  // [hi/lo][m][k], pad to 40 halfs (80B rows)
  __shared__ F16 Bsh[2][128][40];
  const int tid  = threadIdx.x;
  const int lane = tid & 63;
  const int w    = tid >> 6;
  const int wm   = w & 1, wn = w >> 1;
  const int l15  = lane & 15, quad = lane >> 4;
  const int rowblk = blockIdx.y * 128, colblk = blockIdx.x * 128;

  f32x4 acc[4][4];
#pragma unroll
  for (int a = 0; a < 4; ++a)
#pragma unroll
    for (int b = 0; b < 4; ++b) acc[a][b] = (f32x4){0.f, 0.f, 0.f, 0.f};

  for (int kt = 0; kt < K; kt += 32) {
    __syncthreads();
#pragma unroll
    for (int cc = 0; cc < 2; ++cc) {
      int c = tid + cc * 256;           // 512 chunks of 16B per array
      int row = c >> 2, ch = c & 3;
      size_t ga = (size_t)(rowblk + row) * K + kt + ch * 8;
      size_t gb = (size_t)(colblk + row) * K + kt + ch * 8;
      *(uint4*)&Ash[0][row][ch * 8] = *(const uint4*)(Ahi + ga);
      *(uint4*)&Ash[1][row][ch * 8] = *(const uint4*)(Alo + ga);
      *(uint4*)&Bsh[0][row][ch * 8] = *(const uint4*)(Bhi + gb);
      *(uint4*)&Bsh[1][row][ch * 8] = *(const uint4*)(Blo + gb);
    }
    __syncthreads();

    f16x8 ah[4], al[4], bh[4], bl[4];
#pragma unroll
    for (int mt = 0; mt < 4; ++mt) {
      ah[mt] = *(const f16x8*)&Ash[0][wm * 64 + mt * 16 + l15][quad * 8];
      al[mt] = *(const f16x8*)&Ash[1][wm * 64 + mt * 16 + l15][quad * 8];
    }
#pragma unroll
    for (int nt = 0; nt < 4; ++nt) {
      bh[nt] = *(const f16x8*)&Bsh[0][wn * 64 + nt * 16 + l15][quad * 8];
      bl[nt] = *(const f16x8*)&Bsh[1][wn * 64 + nt * 16 + l15][quad * 8];
    }
#pragma unroll
    for (int mt = 0; mt < 4; ++mt)
#pragma unroll
      for (int nt = 0; nt < 4; ++nt) {
        acc[mt][nt] = __builtin_amdgcn_mfma_f32_16x16x32_f16(ah[mt], bh[nt], acc[mt][nt], 0, 0, 0);
        acc[mt][nt] = __builtin_amdgcn_mfma_f32_16x16x32_f16(al[mt], bh[nt], acc[mt][nt], 0, 0, 0);
        acc[mt][nt] = __builtin_amdgcn_mfma_f32_16x16x32_f16(ah[mt], bl[nt], acc[mt][nt], 0, 0, 0);
      }
  }

#pragma unroll
  for (int nt = 0; nt < 4; ++nt) {
    int cg = colblk + wn * 64 + nt * 16 + l15;
    float bv = bias[cg];
#pragma unroll
    for (int mt = 0; mt < 4; ++mt)
#pragma unroll
      for (int i = 0; i < 4; ++i) {
        int rg = rowblk + wm * 64 + mt * 16 + quad * 4 + i;
        C[(size_t)rg * N + cg] = acc[mt][nt][i] + bv;
      }
  }
}

// ---------------------------------------------------------------------------
// RoPE2D + split QKV[8192,2304] fp32 -> q_hi,q_lo (scaled by 0.125), k_hi,
// v_h fp16, each [B,H,N,Dh].
// ---------------------------------------------------------------------------
__global__ __launch_bounds__(256)
void rope_split(const float* __restrict__ qkv, const int* __restrict__ pos2d,
                F16* __restrict__ qh, F16* __restrict__ ql,
                F16* __restrict__ kh, F16* __restrict__ vh, int num_img) {
  const int n = blockIdx.x;
  const int b = blockIdx.y;
  const float* base = qkv + (size_t)(b * NN + n) * QKV3;
  const bool img = (n < num_img);
  float py = 0.f, px = 0.f;
  if (img) {
    py = (float)pos2d[(b * num_img + n) * 2 + 0];
    px = (float)pos2d[(b * num_img + n) * 2 + 1];
  }
  for (int e = threadIdx.x; e < QKV3; e += 256) {
    int s   = e / CC;
    int rem = e - s * CC;
    int h   = rem >> 6;
    int d   = rem & 63;
    float t = base[e];
    float outv;
    if (s < 2 && img) {
      int half = d >> 5;
      int j    = d & 31;
      int i16  = j & 15;
      float pos = half ? px : py;
      // inv_freq = 100^(-i/16) = 2^(-i * log2(100)/16)
      float inv = exp2f(-(float)i16 * 0.41524101186092029f);
      float ang = pos * inv;
      float sn, cs;
      __sincosf(ang, &sn, &cs);
      int pd = (j < 16) ? d + 16 : d - 16;
      float t2 = base[s * CC + h * 64 + pd];
      float rot = (j < 16) ? -t2 : t2;
      outv = t * cs + rot * sn;
    } else {
      outv = t;
    }
    size_t idx = ((size_t)(b * HH + h) * NN + n) * DH + d;
    if (s == 0) {
      float sv = outv * 0.125f;  // fold softmax scale into q
      F16 hv = (F16)sv;
      qh[idx] = hv;
      ql[idx] = (F16)(sv - (float)hv);
    } else if (s == 1) {
      kh[idx] = (F16)outv;
    } else {
      vh[idx] = (F16)outv;
    }
  }
}

// ---------------------------------------------------------------------------
// MFMA flash attention. Block = 4 waves; 64 queries/block (16/wave);
// K-tiles of 64, online softmax in fp32 on MFMA C-layout fragments.
// S = (q_hi+q_lo) . k_hi  (2-term);  O += P(fp16) @ V(fp16).
// Epilogue writes attention output split to fp16 hi/lo for the proj GEMM.
// ---------------------------------------------------------------------------
__global__ __launch_bounds__(256)
void attn_mfma(const F16* __restrict__ Qh, const F16* __restrict__ Ql,
               const F16* __restrict__ Kh, const F16* __restrict__ Vh,
               F16* __restrict__ AOhi, F16* __restrict__ AOlo) {
  __shared__ F16 Ksh[64][72];      // [key][d] (pre-loop: Q_hi [q][d])
  __shared__ F16 Vt[64][72];       // [d][kk]  (pre-loop: Q_lo [q][d])
  __shared__ F16 Psh[4][16][72];   // per-wave P [q_local][kk]

  const int tid  = threadIdx.x;
  const int lane = tid & 63;
  const int w    = tid >> 6;
  const int l15  = lane & 15, quad = lane >> 4;
  const int qt = blockIdx.x;   // 0..15
  const int bh = blockIdx.y;   // 0..95
  const size_t base = (size_t)bh * NN * DH;

  // stage Q (hi into Ksh, lo into Vt), read register fragments
  const F16* qhb = Qh + base + (size_t)qt * 64 * DH;
  const F16* qlb = Ql + base + (size_t)qt * 64 * DH;
#pragma unroll
  for (int cc = 0; cc < 2; ++cc) {
    int c = tid + cc * 256;         // 512 chunks of 16B
    int row = c >> 3, ch = c & 7;
    *(uint4*)&Ksh[row][ch * 8] = *(const uint4*)(qhb + row * DH + ch * 8);
    *(uint4*)&Vt[row][ch * 8]  = *(const uint4*)(qlb + row * DH + ch * 8);
  }
  __syncthreads();
  f16x8 qfh[2], qfl[2];
#pragma unroll
  for (int st = 0; st < 2; ++st) {
    qfh[st] = *(const f16x8*)&Ksh[w * 16 + l15][st * 32 + quad * 8];
    qfl[st] = *(const f16x8*)&Vt[w * 16 + l15][st * 32 + quad * 8];
  }
  __syncthreads();  // everyone done reading Q before staging overwrites

  f32x4 o[4];
  float m_i[4], l_i[4];
#pragma unroll
  for (int g = 0; g < 4; ++g) o[g] = (f32x4){0.f, 0.f, 0.f, 0.f};
#pragma unroll
  for (int i = 0; i < 4; ++i) { m_i[i] = -1e30f; l_i[i] = 0.f; }

  for (int kt = 0; kt < NN; kt += 64) {
    // stage K tile [key][d] and V tile transposed [d][kk]
    const F16* kb = Kh + base + (size_t)kt * DH;
    const F16* vb = Vh + base + (size_t)kt * DH;
#pragma unroll
    for (int cc = 0; cc < 2; ++cc) {
      int c = tid + cc * 256;
      int row = c >> 3, ch = c & 7;
      *(uint4*)&Ksh[row][ch * 8] = *(const uint4*)(kb + row * DH + ch * 8);
      int kk = c & 63, dc = c >> 6;          // dc 0..7 across both cc passes
      uint4 vv = *(const uint4*)(vb + kk * DH + dc * 8);
      const F16* vp = (const F16*)&vv;
#pragma unroll
      for (int t = 0; t < 8; ++t) Vt[dc * 8 + t][kk] = vp[t];
    }
    __syncthreads();

    // S = Q . K^T : 4 key-groups x 2 d-steps x (hi+lo)
    f32x4 s[4];
#pragma unroll
    for (int g = 0; g < 4; ++g) s[g] = (f32x4){0.f, 0.f, 0.f, 0.f};
#pragma unroll
    for (int g = 0; g < 4; ++g)
#pragma unroll
      for (int st = 0; st < 2; ++st) {
        f16x8 kf = *(const f16x8*)&Ksh[g * 16 + l15][st * 32 + quad * 8];
        s[g] = __builtin_amdgcn_mfma_f32_16x16x32_f16(qfh[st], kf, s[g], 0, 0, 0);
        s[g] = __builtin_amdgcn_mfma_f32_16x16x32_f16(qfl[st], kf, s[g], 0, 0, 0);
      }

    // online softmax; lane owns rows quad*4+i, cols g*16+l15
    float p[4][4];
#pragma unroll
    for (int i = 0; i < 4; ++i) {
      float rm = fmaxf(fmaxf(s[0][i], s[1][i]), fmaxf(s[2][i], s[3][i]));
#pragma unroll
      for (int off = 1; off < 16; off <<= 1)
        rm = fmaxf(rm, __shfl_xor(rm, off, 64));
      float mn = fmaxf(m_i[i], rm);
      float alpha = __expf(m_i[i] - mn);
      float rs = 0.f;
#pragma unroll
      for (int g = 0; g < 4; ++g) {
        p[g][i] = __expf(s[g][i] - mn);
        rs += p[g][i];
      }
#pragma unroll
      for (int off = 1; off < 16; off <<= 1)
        rs += __shfl_xor(rs, off, 64);
      l_i[i] = l_i[i] * alpha + rs;
      m_i[i] = mn;
#pragma unroll
      for (int g = 0; g < 4; ++g) o[g][i] *= alpha;
    }

    // C-layout P -> A-layout via wave-private LDS (no barrier needed)
#pragma unroll
    for (int i = 0; i < 4; ++i)
#pragma unroll
      for (int g = 0; g < 4; ++g)
        Psh[w][quad * 4 + i][g * 16 + l15] = (F16)p[g][i];

    f16x8 pf[2];
    pf[0] = *(const f16x8*)&Psh[w][l15][quad * 8];
    pf[1] = *(const f16x8*)&Psh[w][l15][32 + quad * 8];

    // O += P @ V
#pragma unroll
    for (int g = 0; g < 4; ++g)
#pragma unroll
      for (int st = 0; st < 2; ++st) {
        f16x8 vf = *(const f16x8*)&Vt[g * 16 + l15][st * 32 + quad * 8];
        o[g] = __builtin_amdgcn_mfma_f32_16x16x32_f16(pf[st], vf, o[g], 0, 0, 0);
      }
    __syncthreads();  // all reads of Ksh/Vt done before next staging
  }

  // epilogue: normalize, split to fp16 hi/lo, store [B,N,C]
  const int b = bh / HH;
  const int h = bh % HH;
#pragma unroll
  for (int i = 0; i < 4; ++i) {
    int n = qt * 64 + w * 16 + quad * 4 + i;
    float invl = 1.0f / l_i[i];
#pragma unroll
    for (int g = 0; g < 4; ++g) {
      float v = o[g][i] * invl;
      F16 hv = (F16)v;
      F16 lv = (F16)(v - (float)hv);
      size_t idx = ((size_t)(b * NN + n)) * CC + h * DH + g * 16 + l15;
      AOhi[idx] = hv;
      AOlo[idx] = lv;
    }
  }
}

// ---------------------------------------------------------------------------
extern "C" void kernel_launch(void* const* d_in, const int* in_sizes, int n_in,
                              void* d_out, int out_size, void* d_ws, size_t ws_size,
                              hipStream_t stream) {
  const float* x      = (const float*)d_in[0];
  const float* qkv_w  = (const float*)d_in[1];
  const float* qkv_b  = (const float*)d_in[2];
  const float* proj_w = (const float*)d_in[3];
  const float* proj_b = (const float*)d_in[4];
  const int*   pos2d  = (const int*)d_in[5];
  const int num_img = in_sizes[5] / (2 * BB);

  char* ws = (char*)d_ws;
  // byte offsets (all 256B aligned)
  float* qkv  = (float*)(ws + 0);                 // 75,497,472 B
  F16* x_hi   = (F16*)(ws + 75497472);            // 12,582,912 B (aliased: ao_hi)
  F16* x_lo   = (F16*)(ws + 88080384);            // 12,582,912 B (aliased: ao_lo)
  F16* wq_hi  = (F16*)(ws + 100663296);           // 3,538,944 B
  F16* wq_lo  = (F16*)(ws + 104202240);
  F16* wp_hi  = (F16*)(ws + 107741184);           // 1,179,648 B
  F16* wp_lo  = (F16*)(ws + 108920832);
  F16* q_hi   = (F16*)(ws + 110100480);           // 12,582,912 B each
  F16* q_lo   = (F16*)(ws + 122683392);
  F16* k_hi   = (F16*)(ws + 135266304);
  F16* v_h    = (F16*)(ws + 147849216);           // end 160,432,128 B
  F16* ao_hi  = x_hi;  // x_hi/x_lo dead after K1
  F16* ao_lo  = x_lo;
  float* out  = (float*)d_out;

  // casts
  split_f32<<<(BB * NN * CC / 4 + 255) / 256, 256, 0, stream>>>(x, x_hi, x_lo, BB * NN * CC / 4);
  split_f32<<<(QKV3 * CC / 4 + 255) / 256, 256, 0, stream>>>(qkv_w, wq_hi, wq_lo, QKV3 * CC / 4);
  split_f32<<<(CC * CC / 4 + 255) / 256, 256, 0, stream>>>(proj_w, wp_hi, wp_lo, CC * CC / 4);

  // K1: QKV = X @ Wqkv^T + b   (M=8192, N=2304, K=768)
  gemm_split<<<dim3(QKV3 / 128, (BB * NN) / 128), 256, 0, stream>>>(
      x_hi, x_lo, wq_hi, wq_lo, qkv_b, qkv, BB * NN, QKV3, CC);

  // K2: RoPE2D + split to fp16 [B,H,N,Dh]
  rope_split<<<dim3(NN, BB), 256, 0, stream>>>(qkv, pos2d, q_hi, q_lo, k_hi, v_h, num_img);

  // K3: MFMA flash attention -> ao hi/lo fp16 [B,N,C]
  attn_mfma<<<dim3(NN / 64, BB * HH), 256, 0, stream>>>(q_hi, q_lo, k_hi, v_h, ao_hi, ao_lo);

  // K4: out = AO @ Wproj^T + b (M=8192, N=768, K=768)
  gemm_split<<<dim3(CC / 128, (BB * NN) / 128), 256, 0, stream>>>(
      ao_hi, ao_lo, wp_hi, wp_lo, proj_b, out, BB * NN, CC, CC);
}

// Round 3
// 336.069 us; speedup vs baseline: 3.0268x; 1.1396x over previous
//
#include <hip/hip_runtime.h>
#include <math.h>

typedef _Float16 F16;
typedef _Float16 f16x8 __attribute__((ext_vector_type(8)));
typedef _Float16 f16x4 __attribute__((ext_vector_type(4)));
typedef float f32x4 __attribute__((ext_vector_type(4)));

#define BB 8
#define NN 1024
#define CC 768
#define HH 12
#define DH 64
#define QKV3 2304

// ---------------------------------------------------------------------------
// Split fp32 -> fp16 hi + fp16 lo (residual). n4 = count of float4 groups.
// ---------------------------------------------------------------------------
__global__ __launch_bounds__(256)
void split_f32(const float* __restrict__ src, F16* __restrict__ hi,
               F16* __restrict__ lo, int n4) {
  int i = blockIdx.x * 256 + threadIdx.x;
  if (i >= n4) return;
  float4 v = ((const float4*)src)[i];
  float a[4] = {v.x, v.y, v.z, v.w};
  f16x4 h, l;
#pragma unroll
  for (int j = 0; j < 4; ++j) {
    h[j] = (F16)a[j];
    l[j] = (F16)(a[j] - (float)h[j]);
  }
  ((f16x4*)hi)[i] = h;
  ((f16x4*)lo)[i] = l;
}

// ---------------------------------------------------------------------------
// Generic split-fp16 MFMA GEMM (used for proj): C = (Ahi+Alo)(Bhi+Blo)^T + b
// ---------------------------------------------------------------------------
__global__ __launch_bounds__(256)
void gemm_split(const F16* __restrict__ Ahi, const F16* __restrict__ Alo,
                const F16* __restrict__ Bhi, const F16* __restrict__ Blo,
                const float* __restrict__ bias, float* __restrict__ C,
                int M, int N, int K) {
  __shared__ F16 Ash[2][128][40];
  __shared__ F16 Bsh[2][128][40];
  const int tid  = threadIdx.x;
  const int lane = tid & 63;
  const int w    = tid >> 6;
  const int wm   = w & 1, wn = w >> 1;
  const int l15  = lane & 15, quad = lane >> 4;
  const int rowblk = blockIdx.y * 128, colblk = blockIdx.x * 128;

  f32x4 acc[4][4];
#pragma unroll
  for (int a = 0; a < 4; ++a)
#pragma unroll
    for (int b = 0; b < 4; ++b) acc[a][b] = (f32x4){0.f, 0.f, 0.f, 0.f};

  for (int kt = 0; kt < K; kt += 32) {
    __syncthreads();
#pragma unroll
    for (int cc = 0; cc < 2; ++cc) {
      int c = tid + cc * 256;
      int row = c >> 2, ch = c & 3;
      size_t ga = (size_t)(rowblk + row) * K + kt + ch * 8;
      size_t gb = (size_t)(colblk + row) * K + kt + ch * 8;
      *(f16x8*)&Ash[0][row][ch * 8] = *(const f16x8*)(Ahi + ga);
      *(f16x8*)&Ash[1][row][ch * 8] = *(const f16x8*)(Alo + ga);
      *(f16x8*)&Bsh[0][row][ch * 8] = *(const f16x8*)(Bhi + gb);
      *(f16x8*)&Bsh[1][row][ch * 8] = *(const f16x8*)(Blo + gb);
    }
    __syncthreads();

    f16x8 ah[4], al[4], bh[4], bl[4];
#pragma unroll
    for (int mt = 0; mt < 4; ++mt) {
      ah[mt] = *(const f16x8*)&Ash[0][wm * 64 + mt * 16 + l15][quad * 8];
      al[mt] = *(const f16x8*)&Ash[1][wm * 64 + mt * 16 + l15][quad * 8];
    }
#pragma unroll
    for (int nt = 0; nt < 4; ++nt) {
      bh[nt] = *(const f16x8*)&Bsh[0][wn * 64 + nt * 16 + l15][quad * 8];
      bl[nt] = *(const f16x8*)&Bsh[1][wn * 64 + nt * 16 + l15][quad * 8];
    }
#pragma unroll
    for (int mt = 0; mt < 4; ++mt)
#pragma unroll
      for (int nt = 0; nt < 4; ++nt) {
        acc[mt][nt] = __builtin_amdgcn_mfma_f32_16x16x32_f16(ah[mt], bh[nt], acc[mt][nt], 0, 0, 0);
        acc[mt][nt] = __builtin_amdgcn_mfma_f32_16x16x32_f16(al[mt], bh[nt], acc[mt][nt], 0, 0, 0);
        acc[mt][nt] = __builtin_amdgcn_mfma_f32_16x16x32_f16(ah[mt], bl[nt], acc[mt][nt], 0, 0, 0);
      }
  }

#pragma unroll
  for (int nt = 0; nt < 4; ++nt) {
    int cg = colblk + wn * 64 + nt * 16 + l15;
    float bv = bias[cg];
#pragma unroll
    for (int mt = 0; mt < 4; ++mt)
#pragma unroll
      for (int i = 0; i < 4; ++i) {
        int rg = rowblk + wm * 64 + mt * 16 + quad * 4 + i;
        C[(size_t)rg * N + cg] = acc[mt][nt][i] + bv;
      }
  }
}

// ---------------------------------------------------------------------------
// QKV GEMM with fused RoPE2D epilogue. M=8192, N=2304, K=768.
// Wave's 64-col tile = one (sec,head); rope pair d^16 = neighboring nt in
// the same lane. Writes q hi/lo (scaled 0.125), k hi, and V TRANSPOSED
// [b,h,d,n] (f16x4 packed over 4 consecutive n).
// ---------------------------------------------------------------------------
__global__ __launch_bounds__(256)
void gemm_qkv_rope(const F16* __restrict__ Ahi, const F16* __restrict__ Alo,
                   const F16* __restrict__ Bhi, const F16* __restrict__ Blo,
                   const float* __restrict__ bias, const int* __restrict__ pos2d,
                   F16* __restrict__ qh, F16* __restrict__ ql,
                   F16* __restrict__ kh, F16* __restrict__ vt, int num_img) {
  __shared__ F16 Ash[2][128][40];
  __shared__ F16 Bsh[2][128][40];
  const int tid  = threadIdx.x;
  const int lane = tid & 63;
  const int w    = tid >> 6;
  const int wm   = w & 1, wn = w >> 1;
  const int l15  = lane & 15, quad = lane >> 4;
  const int rowblk = blockIdx.y * 128, colblk = blockIdx.x * 128;

  f32x4 acc[4][4];
#pragma unroll
  for (int a = 0; a < 4; ++a)
#pragma unroll
    for (int b = 0; b < 4; ++b) acc[a][b] = (f32x4){0.f, 0.f, 0.f, 0.f};

  for (int kt = 0; kt < CC; kt += 32) {
    __syncthreads();
#pragma unroll
    for (int cc = 0; cc < 2; ++cc) {
      int c = tid + cc * 256;
      int row = c >> 2, ch = c & 3;
      size_t ga = (size_t)(rowblk + row) * CC + kt + ch * 8;
      size_t gb = (size_t)(colblk + row) * CC + kt + ch * 8;
      *(f16x8*)&Ash[0][row][ch * 8] = *(const f16x8*)(Ahi + ga);
      *(f16x8*)&Ash[1][row][ch * 8] = *(const f16x8*)(Alo + ga);
      *(f16x8*)&Bsh[0][row][ch * 8] = *(const f16x8*)(Bhi + gb);
      *(f16x8*)&Bsh[1][row][ch * 8] = *(const f16x8*)(Blo + gb);
    }
    __syncthreads();

    f16x8 ah[4], al[4], bh[4], bl[4];
#pragma unroll
    for (int mt = 0; mt < 4; ++mt) {
      ah[mt] = *(const f16x8*)&Ash[0][wm * 64 + mt * 16 + l15][quad * 8];
      al[mt] = *(const f16x8*)&Ash[1][wm * 64 + mt * 16 + l15][quad * 8];
    }
#pragma unroll
    for (int nt = 0; nt < 4; ++nt) {
      bh[nt] = *(const f16x8*)&Bsh[0][wn * 64 + nt * 16 + l15][quad * 8];
      bl[nt] = *(const f16x8*)&Bsh[1][wn * 64 + nt * 16 + l15][quad * 8];
    }
#pragma unroll
    for (int mt = 0; mt < 4; ++mt)
#pragma unroll
      for (int nt = 0; nt < 4; ++nt) {
        acc[mt][nt] = __builtin_amdgcn_mfma_f32_16x16x32_f16(ah[mt], bh[nt], acc[mt][nt], 0, 0, 0);
        acc[mt][nt] = __builtin_amdgcn_mfma_f32_16x16x32_f16(al[mt], bh[nt], acc[mt][nt], 0, 0, 0);
        acc[mt][nt] = __builtin_amdgcn_mfma_f32_16x16x32_f16(ah[mt], bl[nt], acc[mt][nt], 0, 0, 0);
      }
  }

  const int sec = colblk / CC;                 // 0=q, 1=k, 2=v (uniform/block)
  const int h   = ((colblk % CC) >> 6) + wn;   // head for this wave
  float bv[4];
#pragma unroll
  for (int nt = 0; nt < 4; ++nt) bv[nt] = bias[colblk + wn * 64 + nt * 16 + l15];

  if (sec == 2) {
    // V: write transposed vt[b,h,d,n], f16x4 over 4 consecutive n
#pragma unroll
    for (int mt = 0; mt < 4; ++mt) {
      int rg0 = rowblk + wm * 64 + mt * 16 + quad * 4;
      int b = rg0 >> 10, n0 = rg0 & 1023;
#pragma unroll
      for (int nt = 0; nt < 4; ++nt) {
        int d = nt * 16 + l15;
        f16x4 pk;
#pragma unroll
        for (int i = 0; i < 4; ++i) pk[i] = (F16)(acc[mt][nt][i] + bv[nt]);
        *(f16x4*)(vt + ((size_t)(b * HH + h) * DH + d) * NN + n0) = pk;
      }
    }
  } else {
    const float inv = exp2f(-(float)l15 * 0.41524101186092029f);  // 100^(-l15/16)
#pragma unroll
    for (int mt = 0; mt < 4; ++mt) {
#pragma unroll
      for (int i = 0; i < 4; ++i) {
        int rg = rowblk + wm * 64 + mt * 16 + quad * 4 + i;
        int b = rg >> 10, n = rg & 1023;
        float a0 = acc[mt][0][i] + bv[0];
        float a1 = acc[mt][1][i] + bv[1];
        float a2 = acc[mt][2][i] + bv[2];
        float a3 = acc[mt][3][i] + bv[3];
        float r0 = a0, r1 = a1, r2 = a2, r3 = a3;
        if (n < num_img) {
          float py = (float)pos2d[((size_t)b * num_img + n) * 2 + 0];
          float px = (float)pos2d[((size_t)b * num_img + n) * 2 + 1];
          float sy, cy, sx, cx;
          __sincosf(py * inv, &sy, &cy);
          __sincosf(px * inv, &sx, &cx);
          r0 = a0 * cy - a1 * sy;   // d<16:   t*cos - t_{d+16}*sin
          r1 = a1 * cy + a0 * sy;   // 16..31: t*cos + t_{d-16}*sin
          r2 = a2 * cx - a3 * sx;   // x-half likewise
          r3 = a3 * cx + a2 * sx;
        }
        size_t idx = ((size_t)(b * HH + h) * NN + n) * DH + l15;
        if (sec == 0) {
          float v0 = r0 * 0.125f, v1 = r1 * 0.125f, v2 = r2 * 0.125f, v3 = r3 * 0.125f;
          F16 h0 = (F16)v0, h1 = (F16)v1, h2 = (F16)v2, h3 = (F16)v3;
          qh[idx] = h0; qh[idx + 16] = h1; qh[idx + 32] = h2; qh[idx + 48] = h3;
          ql[idx]      = (F16)(v0 - (float)h0);
          ql[idx + 16] = (F16)(v1 - (float)h1);
          ql[idx + 32] = (F16)(v2 - (float)h2);
          ql[idx + 48] = (F16)(v3 - (float)h3);
        } else {
          kh[idx] = (F16)r0; kh[idx + 16] = (F16)r1;
          kh[idx + 32] = (F16)r2; kh[idx + 48] = (F16)r3;
        }
      }
    }
  }
}

// ---------------------------------------------------------------------------
// MFMA flash attention, S^T formulation. Block: 4 waves, 128 q (32/wave).
// S^T = K·Q^T -> lane holds 16 kk-values of ONE q column (q=lane&15):
// softmax = 2 shuffles; P written as [q][kk] with f16x4 contiguity; PV uses
// A = V^T (from vt[b,h,d,n]), B = P -> O^T, epilogue packs f16x4 hi/lo.
// ---------------------------------------------------------------------------
__global__ __launch_bounds__(256)
void attn_mfma(const F16* __restrict__ Qh, const F16* __restrict__ Ql,
               const F16* __restrict__ Kh, const F16* __restrict__ Vt,
               F16* __restrict__ AOhi, F16* __restrict__ AOlo) {
  __shared__ F16 Ks[2][64][40];       // [d-half][key][d%32], pad 40
  __shared__ F16 Vs[2][64][40];       // [kk-half][d][kk%32]
  __shared__ F16 Ps[2][4][32][40];    // [kk-half][wave][q_local][kk%32]

  const int tid  = threadIdx.x;
  const int lane = tid & 63;
  const int w    = tid >> 6;
  const int l15  = lane & 15, quad = lane >> 4;
  const int bh   = blockIdx.y;
  const int q0   = blockIdx.x * 128 + w * 32;
  const size_t kqbase = (size_t)bh * NN * DH;   // q/k [bh][n][d]
  const size_t vbase  = (size_t)bh * DH * NN;   // vt  [bh][d][n]

  // Q fragments straight from global (B-operand layout: row q0+qn*16+l15)
  f16x8 qfh[2][2], qfl[2][2];
#pragma unroll
  for (int qn = 0; qn < 2; ++qn)
#pragma unroll
    for (int st = 0; st < 2; ++st) {
      size_t off = kqbase + (size_t)(q0 + qn * 16 + l15) * DH + st * 32 + quad * 8;
      qfh[qn][st] = *(const f16x8*)(Qh + off);
      qfl[qn][st] = *(const f16x8*)(Ql + off);
    }

  f32x4 o[2][4];
  float m_i[2], l_i[2];
#pragma unroll
  for (int qn = 0; qn < 2; ++qn) {
    m_i[qn] = -1e30f; l_i[qn] = 0.f;
#pragma unroll
    for (int gd = 0; gd < 4; ++gd) o[qn][gd] = (f32x4){0.f, 0.f, 0.f, 0.f};
  }

  for (int kt = 0; kt < NN; kt += 64) {
    __syncthreads();
#pragma unroll
    for (int cc = 0; cc < 2; ++cc) {
      int c = tid + cc * 256;
      int row = c >> 3, ch = c & 7;
      *(f16x8*)&Ks[ch >> 2][row][(ch & 3) * 8] =
          *(const f16x8*)(Kh + kqbase + (size_t)(kt + row) * DH + ch * 8);
      *(f16x8*)&Vs[ch >> 2][row][(ch & 3) * 8] =
          *(const f16x8*)(Vt + vbase + (size_t)row * NN + kt + ch * 8);
    }
    __syncthreads();

    f16x8 kf[4][2], vf[4][2];
#pragma unroll
    for (int g = 0; g < 4; ++g)
#pragma unroll
      for (int st = 0; st < 2; ++st) {
        kf[g][st] = *(const f16x8*)&Ks[st][g * 16 + l15][quad * 8];
        vf[g][st] = *(const f16x8*)&Vs[st][g * 16 + l15][quad * 8];
      }

#pragma unroll
    for (int qn = 0; qn < 2; ++qn) {
      // S^T tiles: rows kk (4 groups of 16), col q = l15
      f32x4 s[4];
#pragma unroll
      for (int g = 0; g < 4; ++g) {
        s[g] = (f32x4){0.f, 0.f, 0.f, 0.f};
#pragma unroll
        for (int st = 0; st < 2; ++st) {
          s[g] = __builtin_amdgcn_mfma_f32_16x16x32_f16(kf[g][st], qfh[qn][st], s[g], 0, 0, 0);
          s[g] = __builtin_amdgcn_mfma_f32_16x16x32_f16(kf[g][st], qfl[qn][st], s[g], 0, 0, 0);
        }
      }
      // online softmax (lane owns q = qn*16+l15; kk = g*16+quad*4+i)
      float rm = -1e30f;
#pragma unroll
      for (int g = 0; g < 4; ++g)
#pragma unroll
        for (int i = 0; i < 4; ++i) rm = fmaxf(rm, s[g][i]);
      rm = fmaxf(rm, __shfl_xor(rm, 16, 64));
      rm = fmaxf(rm, __shfl_xor(rm, 32, 64));
      float mn = fmaxf(m_i[qn], rm);
      float alpha = __expf(m_i[qn] - mn);
      float rs = 0.f;
      f16x4 pk[4];
#pragma unroll
      for (int g = 0; g < 4; ++g)
#pragma unroll
        for (int i = 0; i < 4; ++i) {
          float p = __expf(s[g][i] - mn);
          rs += p;
          pk[g][i] = (F16)p;
        }
      rs += __shfl_xor(rs, 16, 64);
      rs += __shfl_xor(rs, 32, 64);
      l_i[qn] = l_i[qn] * alpha + rs;
      m_i[qn] = mn;
#pragma unroll
      for (int gd = 0; gd < 4; ++gd) o[qn][gd] *= alpha;

      // P -> LDS [q][kk] (f16x4 contiguous), wave-private
#pragma unroll
      for (int g = 0; g < 4; ++g)
        *(f16x4*)&Ps[g >> 1][w][qn * 16 + l15][(g & 1) * 16 + quad * 4] = pk[g];
      f16x8 pf0 = *(const f16x8*)&Ps[0][w][qn * 16 + l15][quad * 8];
      f16x8 pf1 = *(const f16x8*)&Ps[1][w][qn * 16 + l15][quad * 8];

      // O^T += V^T · P^T  (A = V^T rows d, B = P rows q)
#pragma unroll
      for (int gd = 0; gd < 4; ++gd) {
        o[qn][gd] = __builtin_amdgcn_mfma_f32_16x16x32_f16(vf[gd][0], pf0, o[qn][gd], 0, 0, 0);
        o[qn][gd] = __builtin_amdgcn_mfma_f32_16x16x32_f16(vf[gd][1], pf1, o[qn][gd], 0, 0, 0);
      }
    }
  }

  // epilogue: O^T C-layout: (d = gd*16+quad*4+i, q = qn*16+l15)
  const int b = bh / HH, h = bh % HH;
#pragma unroll
  for (int qn = 0; qn < 2; ++qn) {
    float invl = 1.0f / l_i[qn];
    int n = q0 + qn * 16 + l15;
#pragma unroll
    for (int gd = 0; gd < 4; ++gd) {
      f16x4 hv, lv;
#pragma unroll
      for (int i = 0; i < 4; ++i) {
        float val = o[qn][gd][i] * invl;
        hv[i] = (F16)val;
        lv[i] = (F16)(val - (float)hv[i]);
      }
      size_t idx = ((size_t)(b * NN + n)) * CC + h * DH + gd * 16 + quad * 4;
      *(f16x4*)(AOhi + idx) = hv;
      *(f16x4*)(AOlo + idx) = lv;
    }
  }
}

// ---------------------------------------------------------------------------
extern "C" void kernel_launch(void* const* d_in, const int* in_sizes, int n_in,
                              void* d_out, int out_size, void* d_ws, size_t ws_size,
                              hipStream_t stream) {
  const float* x      = (const float*)d_in[0];
  const float* qkv_w  = (const float*)d_in[1];
  const float* qkv_b  = (const float*)d_in[2];
  const float* proj_w = (const float*)d_in[3];
  const float* proj_b = (const float*)d_in[4];
  const int*   pos2d  = (const int*)d_in[5];
  const int num_img = in_sizes[5] / (2 * BB);

  char* ws = (char*)d_ws;
  F16* x_hi  = (F16*)(ws + 0);            // 12,582,912 B
  F16* x_lo  = (F16*)(ws + 12582912);
  F16* wq_hi = (F16*)(ws + 25165824);     // 3,538,944 B
  F16* wq_lo = (F16*)(ws + 28704768);
  F16* wp_hi = (F16*)(ws + 32243712);     // 1,179,648 B
  F16* wp_lo = (F16*)(ws + 33423360);
  F16* q_hi  = (F16*)(ws + 34603008);     // 12,582,912 B each
  F16* q_lo  = (F16*)(ws + 47185920);
  F16* k_hi  = (F16*)(ws + 59768832);
  F16* vt    = (F16*)(ws + 72351744);     // V transposed [b,h,d,n]
  F16* ao_hi = (F16*)(ws + 84934656);
  F16* ao_lo = (F16*)(ws + 97517568);     // end 110,100,480 B
  float* out = (float*)d_out;

  split_f32<<<(BB * NN * CC / 4 + 255) / 256, 256, 0, stream>>>(x, x_hi, x_lo, BB * NN * CC / 4);
  split_f32<<<(QKV3 * CC / 4 + 255) / 256, 256, 0, stream>>>(qkv_w, wq_hi, wq_lo, QKV3 * CC / 4);
  split_f32<<<(CC * CC / 4 + 255) / 256, 256, 0, stream>>>(proj_w, wp_hi, wp_lo, CC * CC / 4);

  // K1: QKV GEMM + fused RoPE2D + split/transpose epilogue
  gemm_qkv_rope<<<dim3(QKV3 / 128, (BB * NN) / 128), 256, 0, stream>>>(
      x_hi, x_lo, wq_hi, wq_lo, qkv_b, pos2d, q_hi, q_lo, k_hi, vt, num_img);

  // K3: MFMA flash attention (S^T form) -> ao hi/lo fp16 [B,N,C]
  attn_mfma<<<dim3(NN / 128, BB * HH), 256, 0, stream>>>(q_hi, q_lo, k_hi, vt, ao_hi, ao_lo);

  // K4: out = AO @ Wproj^T + b
  gemm_split<<<dim3(CC / 128, (BB * NN) / 128), 256, 0, stream>>>(
      ao_hi, ao_lo, wp_hi, wp_lo, proj_b, out, BB * NN, CC, CC);
}

// Round 4
// 283.034 us; speedup vs baseline: 3.5939x; 1.1874x over previous
//
#include <hip/hip_runtime.h>
#include <math.h>

typedef _Float16 F16;
typedef _Float16 f16x8 __attribute__((ext_vector_type(8)));
typedef _Float16 f16x4 __attribute__((ext_vector_type(4)));
typedef float f32x4 __attribute__((ext_vector_type(4)));

#define BB 8
#define NN 1024
#define CC 768
#define HH 12
#define DH 64
#define QKV3 2304

// async global->LDS, 16B per lane; LDS dest = uniform base + lane*16
__device__ __forceinline__ void gld16(const F16* g, F16* l) {
  __builtin_amdgcn_global_load_lds(
      (const __attribute__((address_space(1))) void*)g,
      (__attribute__((address_space(3))) void*)l, 16, 0, 0);
}

// fragment read from paired-row swizzled LDS (logical rows = 32 halfs / 64B;
// two logical rows share one 128B LDS row; chunk swizzled by (m>>1)&3)
__device__ __forceinline__ f16x8 ldsP(const F16* base, int m, int quad) {
  return *(const f16x8*)(base + ((m >> 1) << 6) +
                         ((((m & 1) << 2) | (quad ^ ((m >> 1) & 3))) << 3));
}
// fragment read from 128B-row swizzled LDS (rows = 64 halfs; chunk ^ (m&7))
__device__ __forceinline__ f16x8 ldsR(const F16* base, int m, int cc) {
  return *(const f16x8*)(base + (m << 6) + ((cc ^ (m & 7)) << 3));
}

// ---------------------------------------------------------------------------
// Converters in one launch: x -> hi/lo split; qkv_w, proj_w -> fp16 round.
// ---------------------------------------------------------------------------
#define NX4 1572864   // 8*1024*768/4
#define NW1 442368    // 2304*768/4
#define NW2 147456    // 768*768/4
__global__ __launch_bounds__(256)
void convert_all(const float* __restrict__ x, const float* __restrict__ w1,
                 const float* __restrict__ w2, F16* __restrict__ xh,
                 F16* __restrict__ xl, F16* __restrict__ w1h,
                 F16* __restrict__ w2h) {
  int i = blockIdx.x * 256 + threadIdx.x;
  if (i < NX4) {
    float4 v = ((const float4*)x)[i];
    float a[4] = {v.x, v.y, v.z, v.w};
    f16x4 h, l;
#pragma unroll
    for (int j = 0; j < 4; ++j) {
      h[j] = (F16)a[j];
      l[j] = (F16)(a[j] - (float)h[j]);
    }
    ((f16x4*)xh)[i] = h;
    ((f16x4*)xl)[i] = l;
  } else if (i < NX4 + NW1) {
    int j = i - NX4;
    float4 v = ((const float4*)w1)[j];
    f16x4 h = {(F16)v.x, (F16)v.y, (F16)v.z, (F16)v.w};
    ((f16x4*)w1h)[j] = h;
  } else if (i < NX4 + NW1 + NW2) {
    int j = i - NX4 - NW1;
    float4 v = ((const float4*)w2)[j];
    f16x4 h = {(F16)v.x, (F16)v.y, (F16)v.z, (F16)v.w};
    ((f16x4*)w2h)[j] = h;
  }
}

// ---------------------------------------------------------------------------
// K1: QKV GEMM (2-term split: (Ah+Al)@W16^T) + fused RoPE2D epilogue.
// M=8192, N=2304, K=768. 128x128 tile, BK=32, global_load_lds staging.
// ---------------------------------------------------------------------------
__global__ __launch_bounds__(256)
void gemm_qkv_rope(const F16* __restrict__ XAh, const F16* __restrict__ XAl,
                   const F16* __restrict__ WQ, const float* __restrict__ bias,
                   const int* __restrict__ pos2d, F16* __restrict__ qh,
                   F16* __restrict__ kh, F16* __restrict__ vt, int num_img) {
  __shared__ alignas(16) F16 sm[3 * 4096];   // Ah | Al | W, 8KB each
  const int tid = threadIdx.x, lane = tid & 63, w = tid >> 6;
  const int wm = w & 1, wn = w >> 1;
  const int l15 = lane & 15, quad = lane >> 4;
  const int rowblk = blockIdx.y * 128, colblk = blockIdx.x * 128;

  // staging lane decomposition (paired-row layout)
  const int rloc = lane >> 3, ploc = lane & 7;
  const int mloc = 2 * rloc + (ploc >> 2);        // logical row 0..15 within 16
  const int cloc = (ploc & 3) ^ (rloc & 3);       // swizzled 16B chunk 0..3

  const F16* gsrc[6];
  F16* ldst[6];
#pragma unroll
  for (int u = 0; u < 6; ++u) {
    int t = w * 6 + u;                            // 24 instrs: 3 parts x 8
    int part = t >> 3, j = t & 7;
    const F16* gb = part == 0 ? XAh + (size_t)rowblk * CC
                  : part == 1 ? XAl + (size_t)rowblk * CC
                              : WQ + (size_t)colblk * CC;
    gsrc[u] = gb + (size_t)(16 * j + mloc) * CC + cloc * 8;
    ldst[u] = sm + part * 4096 + j * 512;
  }

  f32x4 acc[4][4];
#pragma unroll
  for (int a = 0; a < 4; ++a)
#pragma unroll
    for (int b = 0; b < 4; ++b) acc[a][b] = (f32x4){0.f, 0.f, 0.f, 0.f};

  for (int kt = 0; kt < CC; kt += 32) {
    __syncthreads();
#pragma unroll
    for (int u = 0; u < 6; ++u) gld16(gsrc[u] + kt, ldst[u]);
    __syncthreads();

    f16x8 afh[4], afl[4], bf[4];
#pragma unroll
    for (int mt = 0; mt < 4; ++mt) {
      int m = wm * 64 + mt * 16 + l15;
      afh[mt] = ldsP(sm, m, quad);
      afl[mt] = ldsP(sm + 4096, m, quad);
    }
#pragma unroll
    for (int nt = 0; nt < 4; ++nt)
      bf[nt] = ldsP(sm + 8192, wn * 64 + nt * 16 + l15, quad);
#pragma unroll
    for (int mt = 0; mt < 4; ++mt)
#pragma unroll
      for (int nt = 0; nt < 4; ++nt) {
        acc[mt][nt] = __builtin_amdgcn_mfma_f32_16x16x32_f16(afh[mt], bf[nt], acc[mt][nt], 0, 0, 0);
        acc[mt][nt] = __builtin_amdgcn_mfma_f32_16x16x32_f16(afl[mt], bf[nt], acc[mt][nt], 0, 0, 0);
      }
  }

  const int sec = colblk / CC;                 // 0=q, 1=k, 2=v
  const int h   = ((colblk % CC) >> 6) + wn;
  float bv[4];
#pragma unroll
  for (int nt = 0; nt < 4; ++nt) bv[nt] = bias[colblk + wn * 64 + nt * 16 + l15];

  if (sec == 2) {
#pragma unroll
    for (int mt = 0; mt < 4; ++mt) {
      int rg0 = rowblk + wm * 64 + mt * 16 + quad * 4;
      int b = rg0 >> 10, n0 = rg0 & 1023;
#pragma unroll
      for (int nt = 0; nt < 4; ++nt) {
        int d = nt * 16 + l15;
        f16x4 pk;
#pragma unroll
        for (int i = 0; i < 4; ++i) pk[i] = (F16)(acc[mt][nt][i] + bv[nt]);
        *(f16x4*)(vt + ((size_t)(b * HH + h) * DH + d) * NN + n0) = pk;
      }
    }
  } else {
    const float inv = exp2f(-(float)l15 * 0.41524101186092029f);  // 100^(-l15/16)
#pragma unroll
    for (int mt = 0; mt < 4; ++mt) {
#pragma unroll
      for (int i = 0; i < 4; ++i) {
        int rg = rowblk + wm * 64 + mt * 16 + quad * 4 + i;
        int b = rg >> 10, n = rg & 1023;
        float a0 = acc[mt][0][i] + bv[0];
        float a1 = acc[mt][1][i] + bv[1];
        float a2 = acc[mt][2][i] + bv[2];
        float a3 = acc[mt][3][i] + bv[3];
        float r0 = a0, r1 = a1, r2 = a2, r3 = a3;
        if (n < num_img) {
          float py = (float)pos2d[((size_t)b * num_img + n) * 2 + 0];
          float px = (float)pos2d[((size_t)b * num_img + n) * 2 + 1];
          float sy, cy, sx, cx;
          __sincosf(py * inv, &sy, &cy);
          __sincosf(px * inv, &sx, &cx);
          r0 = a0 * cy - a1 * sy;
          r1 = a1 * cy + a0 * sy;
          r2 = a2 * cx - a3 * sx;
          r3 = a3 * cx + a2 * sx;
        }
        size_t idx = ((size_t)(b * HH + h) * NN + n) * DH + l15;
        if (sec == 0) {
          qh[idx]      = (F16)(r0 * 0.125f);
          qh[idx + 16] = (F16)(r1 * 0.125f);
          qh[idx + 32] = (F16)(r2 * 0.125f);
          qh[idx + 48] = (F16)(r3 * 0.125f);
        } else {
          kh[idx] = (F16)r0; kh[idx + 16] = (F16)r1;
          kh[idx + 32] = (F16)r2; kh[idx + 48] = (F16)r3;
        }
      }
    }
  }
}

// ---------------------------------------------------------------------------
// K4: out = (AOh+AOl) @ W16^T + b. M=8192, N=768, K=768. 128x64 tile.
// ---------------------------------------------------------------------------
__global__ __launch_bounds__(256)
void gemm_proj(const F16* __restrict__ AOh, const F16* __restrict__ AOl,
               const F16* __restrict__ WP, const float* __restrict__ bias,
               float* __restrict__ out) {
  __shared__ alignas(16) F16 sm[2 * 4096 + 2048];  // Ah | Al | W(64 rows)
  const int tid = threadIdx.x, lane = tid & 63, w = tid >> 6;
  const int wm = w & 1, wn = w >> 1;
  const int l15 = lane & 15, quad = lane >> 4;
  const int rowblk = blockIdx.y * 128, colblk = blockIdx.x * 64;

  const int rloc = lane >> 3, ploc = lane & 7;
  const int mloc = 2 * rloc + (ploc >> 2);
  const int cloc = (ploc & 3) ^ (rloc & 3);

  const F16* gsrc[5];
  F16* ldst[5];
#pragma unroll
  for (int u = 0; u < 5; ++u) {
    int t = w * 5 + u;                 // 20 instrs: A 8, Al 8, W 4
    const F16* gb;
    F16* lb;
    int j;
    if (t < 8)       { gb = AOh + (size_t)rowblk * CC; j = t;      lb = sm; }
    else if (t < 16) { gb = AOl + (size_t)rowblk * CC; j = t - 8;  lb = sm + 4096; }
    else             { gb = WP  + (size_t)colblk * CC; j = t - 16; lb = sm + 8192; }
    gsrc[u] = gb + (size_t)(16 * j + mloc) * CC + cloc * 8;
    ldst[u] = lb + j * 512;
  }

  f32x4 acc[4][2];
#pragma unroll
  for (int a = 0; a < 4; ++a)
#pragma unroll
    for (int b = 0; b < 2; ++b) acc[a][b] = (f32x4){0.f, 0.f, 0.f, 0.f};

  for (int kt = 0; kt < CC; kt += 32) {
    __syncthreads();
#pragma unroll
    for (int u = 0; u < 5; ++u) gld16(gsrc[u] + kt, ldst[u]);
    __syncthreads();

    f16x8 afh[4], afl[4], bf[2];
#pragma unroll
    for (int mt = 0; mt < 4; ++mt) {
      int m = wm * 64 + mt * 16 + l15;
      afh[mt] = ldsP(sm, m, quad);
      afl[mt] = ldsP(sm + 4096, m, quad);
    }
#pragma unroll
    for (int nt = 0; nt < 2; ++nt)
      bf[nt] = ldsP(sm + 8192, wn * 32 + nt * 16 + l15, quad);
#pragma unroll
    for (int mt = 0; mt < 4; ++mt)
#pragma unroll
      for (int nt = 0; nt < 2; ++nt) {
        acc[mt][nt] = __builtin_amdgcn_mfma_f32_16x16x32_f16(afh[mt], bf[nt], acc[mt][nt], 0, 0, 0);
        acc[mt][nt] = __builtin_amdgcn_mfma_f32_16x16x32_f16(afl[mt], bf[nt], acc[mt][nt], 0, 0, 0);
      }
  }

#pragma unroll
  for (int nt = 0; nt < 2; ++nt) {
    int cg = colblk + wn * 32 + nt * 16 + l15;
    float bv = bias[cg];
#pragma unroll
    for (int mt = 0; mt < 4; ++mt)
#pragma unroll
      for (int i = 0; i < 4; ++i) {
        int rg = rowblk + wm * 64 + mt * 16 + quad * 4 + i;
        out[(size_t)rg * CC + cg] = acc[mt][nt][i] + bv;
      }
  }
}

// ---------------------------------------------------------------------------
// K3: MFMA flash attention, S^T form, 1-term QK. Block: 4 waves, 128 q.
// K/V staged via global_load_lds into 128B-row swizzled LDS.
// ---------------------------------------------------------------------------
__global__ __launch_bounds__(256)
void attn_mfma(const F16* __restrict__ Qh, const F16* __restrict__ Kh,
               const F16* __restrict__ Vt, F16* __restrict__ AOhi,
               F16* __restrict__ AOlo) {
  __shared__ alignas(16) F16 Ks[4096];       // 64 keys x 64 halfs, swizzled
  __shared__ alignas(16) F16 Vs[4096];       // 64 d    x 64 halfs, swizzled
  __shared__ alignas(16) F16 Ps[2][4][32][40];

  const int tid = threadIdx.x, lane = tid & 63, w = tid >> 6;
  const int l15 = lane & 15, quad = lane >> 4;
  const int bh = blockIdx.y;
  const int q0 = blockIdx.x * 128 + w * 32;
  const size_t kqbase = (size_t)bh * NN * DH;
  const size_t vbase  = (size_t)bh * DH * NN;

  const int rloc = lane >> 3, ploc = lane & 7;
  const int cK = ploc ^ rloc;                 // swizzled chunk (row&7 == rloc)

  f16x8 qf[2][2];
#pragma unroll
  for (int qn = 0; qn < 2; ++qn)
#pragma unroll
    for (int st = 0; st < 2; ++st)
      qf[qn][st] = *(const f16x8*)(Qh + kqbase +
                    (size_t)(q0 + qn * 16 + l15) * DH + st * 32 + quad * 8);

  f32x4 o[2][4];
  float m_i[2], l_i[2];
#pragma unroll
  for (int qn = 0; qn < 2; ++qn) {
    m_i[qn] = -1e30f; l_i[qn] = 0.f;
#pragma unroll
    for (int gd = 0; gd < 4; ++gd) o[qn][gd] = (f32x4){0.f, 0.f, 0.f, 0.f};
  }

  for (int kt = 0; kt < NN; kt += 64) {
    __syncthreads();
#pragma unroll
    for (int u = 0; u < 4; ++u) {
      int t = w * 4 + u, j = t & 7;          // 16 instrs: K 8, V 8
      if (t < 8)
        gld16(Kh + kqbase + (size_t)(kt + 8 * j + rloc) * DH + cK * 8, Ks + j * 512);
      else
        gld16(Vt + vbase + (size_t)(8 * j + rloc) * NN + kt + cK * 8, Vs + j * 512);
    }
    __syncthreads();

    f16x8 kf[4][2], vf[4][2];
#pragma unroll
    for (int g = 0; g < 4; ++g)
#pragma unroll
      for (int st = 0; st < 2; ++st) {
        kf[g][st] = ldsR(Ks, g * 16 + l15, st * 4 + quad);
        vf[g][st] = ldsR(Vs, g * 16 + l15, st * 4 + quad);
      }

#pragma unroll
    for (int qn = 0; qn < 2; ++qn) {
      f32x4 s[4];
#pragma unroll
      for (int g = 0; g < 4; ++g) {
        s[g] = (f32x4){0.f, 0.f, 0.f, 0.f};
#pragma unroll
        for (int st = 0; st < 2; ++st)
          s[g] = __builtin_amdgcn_mfma_f32_16x16x32_f16(kf[g][st], qf[qn][st], s[g], 0, 0, 0);
      }
      float rm = -1e30f;
#pragma unroll
      for (int g = 0; g < 4; ++g)
#pragma unroll
        for (int i = 0; i < 4; ++i) rm = fmaxf(rm, s[g][i]);
      rm = fmaxf(rm, __shfl_xor(rm, 16, 64));
      rm = fmaxf(rm, __shfl_xor(rm, 32, 64));
      float mn = fmaxf(m_i[qn], rm);
      float alpha = __expf(m_i[qn] - mn);
      float rs = 0.f;
      f16x4 pk[4];
#pragma unroll
      for (int g = 0; g < 4; ++g)
#pragma unroll
        for (int i = 0; i < 4; ++i) {
          float p = __expf(s[g][i] - mn);
          rs += p;
          pk[g][i] = (F16)p;
        }
      rs += __shfl_xor(rs, 16, 64);
      rs += __shfl_xor(rs, 32, 64);
      l_i[qn] = l_i[qn] * alpha + rs;
      m_i[qn] = mn;
#pragma unroll
      for (int gd = 0; gd < 4; ++gd) o[qn][gd] *= alpha;

#pragma unroll
      for (int g = 0; g < 4; ++g)
        *(f16x4*)&Ps[g >> 1][w][qn * 16 + l15][(g & 1) * 16 + quad * 4] = pk[g];
      f16x8 pf0 = *(const f16x8*)&Ps[0][w][qn * 16 + l15][quad * 8];
      f16x8 pf1 = *(const f16x8*)&Ps[1][w][qn * 16 + l15][quad * 8];

#pragma unroll
      for (int gd = 0; gd < 4; ++gd) {
        o[qn][gd] = __builtin_amdgcn_mfma_f32_16x16x32_f16(vf[gd][0], pf0, o[qn][gd], 0, 0, 0);
        o[qn][gd] = __builtin_amdgcn_mfma_f32_16x16x32_f16(vf[gd][1], pf1, o[qn][gd], 0, 0, 0);
      }
    }
  }

  const int b = bh / HH, h = bh % HH;
#pragma unroll
  for (int qn = 0; qn < 2; ++qn) {
    float invl = 1.0f / l_i[qn];
    int n = q0 + qn * 16 + l15;
#pragma unroll
    for (int gd = 0; gd < 4; ++gd) {
      f16x4 hv, lv;
#pragma unroll
      for (int i = 0; i < 4; ++i) {
        float val = o[qn][gd][i] * invl;
        hv[i] = (F16)val;
        lv[i] = (F16)(val - (float)hv[i]);
      }
      size_t idx = ((size_t)(b * NN + n)) * CC + h * DH + gd * 16 + quad * 4;
      *(f16x4*)(AOhi + idx) = hv;
      *(f16x4*)(AOlo + idx) = lv;
    }
  }
}

// ---------------------------------------------------------------------------
extern "C" void kernel_launch(void* const* d_in, const int* in_sizes, int n_in,
                              void* d_out, int out_size, void* d_ws, size_t ws_size,
                              hipStream_t stream) {
  const float* x      = (const float*)d_in[0];
  const float* qkv_w  = (const float*)d_in[1];
  const float* qkv_b  = (const float*)d_in[2];
  const float* proj_w = (const float*)d_in[3];
  const float* proj_b = (const float*)d_in[4];
  const int*   pos2d  = (const int*)d_in[5];
  const int num_img = in_sizes[5] / (2 * BB);

  char* ws = (char*)d_ws;
  F16* x_hi  = (F16*)(ws + 0);            // 12,582,912 B
  F16* x_lo  = (F16*)(ws + 12582912);
  F16* wq_h  = (F16*)(ws + 25165824);     // 3,538,944 B
  F16* wp_h  = (F16*)(ws + 28704768);     // 1,179,648 B
  F16* q_hi  = (F16*)(ws + 29884416);     // 12,582,912 B each
  F16* k_hi  = (F16*)(ws + 42467328);
  F16* vt    = (F16*)(ws + 55050240);     // V transposed [b,h,d,n]
  F16* ao_hi = (F16*)(ws + 67633152);
  F16* ao_lo = (F16*)(ws + 80216064);     // end 92,798,976 B
  float* out = (float*)d_out;

  convert_all<<<(NX4 + NW1 + NW2 + 255) / 256, 256, 0, stream>>>(
      x, qkv_w, proj_w, x_hi, x_lo, wq_h, wp_h);

  gemm_qkv_rope<<<dim3(QKV3 / 128, (BB * NN) / 128), 256, 0, stream>>>(
      x_hi, x_lo, wq_h, qkv_b, pos2d, q_hi, k_hi, vt, num_img);

  attn_mfma<<<dim3(NN / 128, BB * HH), 256, 0, stream>>>(
      q_hi, k_hi, vt, ao_hi, ao_lo);

  gemm_proj<<<dim3(CC / 64, (BB * NN) / 128), 256, 0, stream>>>(
      ao_hi, ao_lo, wp_h, proj_b, out);
}

// Round 5
// 220.260 us; speedup vs baseline: 4.6182x; 1.2850x over previous
//
#include <hip/hip_runtime.h>
#include <math.h>

typedef _Float16 F16;
typedef _Float16 f16x8 __attribute__((ext_vector_type(8)));
typedef _Float16 f16x4 __attribute__((ext_vector_type(4)));
typedef float f32x4 __attribute__((ext_vector_type(4)));

#define BB 8
#define NN 1024
#define CC 768
#define HH 12
#define DH 64
#define QKV3 2304

// async global->LDS, 16B/lane; LDS dest = wave-uniform base + lane*16
__device__ __forceinline__ void gld16(const F16* g, F16* l) {
  __builtin_amdgcn_global_load_lds(
      (const __attribute__((address_space(1))) void*)g,
      (__attribute__((address_space(3))) void*)l, 16, 0, 0);
}

// read f16x8 from 128B-row swizzled LDS: row m (64 halfs), global chunk cc
// stored at position cc ^ (m&7)
__device__ __forceinline__ f16x8 ldsR(const F16* base, int m, int cc) {
  return *(const f16x8*)(base + (m << 6) + ((cc ^ (m & 7)) << 3));
}

__device__ __forceinline__ uint2 shfl_u2(uint2 v, int src) {
  uint2 r;
  r.x = (unsigned)__shfl((int)v.x, src, 64);
  r.y = (unsigned)__shfl((int)v.y, src, 64);
  return r;
}

// ---------------------------------------------------------------------------
// Converters: x, qkv_w, proj_w -> fp16 (single term each)
// ---------------------------------------------------------------------------
#define NX4 1572864   // 8*1024*768/4
#define NW1 442368    // 2304*768/4
#define NW2 147456    // 768*768/4
__global__ __launch_bounds__(256)
void convert_all(const float* __restrict__ x, const float* __restrict__ w1,
                 const float* __restrict__ w2, F16* __restrict__ xh,
                 F16* __restrict__ w1h, F16* __restrict__ w2h) {
  int i = blockIdx.x * 256 + threadIdx.x;
  if (i < NX4) {
    float4 v = ((const float4*)x)[i];
    f16x4 h = {(F16)v.x, (F16)v.y, (F16)v.z, (F16)v.w};
    ((f16x4*)xh)[i] = h;
  } else if (i < NX4 + NW1) {
    int j = i - NX4;
    float4 v = ((const float4*)w1)[j];
    f16x4 h = {(F16)v.x, (F16)v.y, (F16)v.z, (F16)v.w};
    ((f16x4*)w1h)[j] = h;
  } else if (i < NX4 + NW1 + NW2) {
    int j = i - NX4 - NW1;
    float4 v = ((const float4*)w2)[j];
    f16x4 h = {(F16)v.x, (F16)v.y, (F16)v.z, (F16)v.w};
    ((f16x4*)w2h)[j] = h;
  }
}

// ---------------------------------------------------------------------------
// K1: QKV GEMM (fp16, fp32-acc) + fused RoPE2D epilogue. M=8192 N=2304 K=768.
// 128x128 tile, BK=64, global_load_lds staging, XCD-panel swizzle.
// ---------------------------------------------------------------------------
__global__ __launch_bounds__(256)
void gemm_qkv_rope(const F16* __restrict__ XA, const F16* __restrict__ WQ,
                   const float* __restrict__ bias, const int* __restrict__ pos2d,
                   F16* __restrict__ qh, F16* __restrict__ kh,
                   F16* __restrict__ vt, int num_img) {
  __shared__ alignas(16) F16 sm[2 * 8192];   // X tile | W tile, 16KB each
  const int tid = threadIdx.x, lane = tid & 63, w = tid >> 6;
  const int wm = w & 1, wn = w >> 1;
  const int l15 = lane & 15, quad = lane >> 4;

  // XCD-panel swizzle: each XCD owns 8 row-stripes x all 18 col-blocks
  const int flat = blockIdx.y * 18 + blockIdx.x;
  const int xcd = flat & 7, g = flat >> 3;     // g in [0,144)
  const int colblk = (g % 18) * 128;
  const int rowblk = (xcd * 8 + g / 18) * 128;

  const int rloc = lane >> 3, ploc = lane & 7;
  const int cK = ploc ^ rloc;                  // swizzled global chunk

  const F16* gsrc[8];
  F16* ldst[8];
#pragma unroll
  for (int u = 0; u < 8; ++u) {
    int t = w * 8 + u;                         // 32 loads: X 16, W 16
    int part = t >> 4, j = t & 15;
    const F16* gb = part ? WQ + (size_t)colblk * CC : XA + (size_t)rowblk * CC;
    gsrc[u] = gb + (size_t)(8 * j + rloc) * CC + cK * 8;
    ldst[u] = sm + part * 8192 + j * 512;
  }

  f32x4 acc[4][4];
#pragma unroll
  for (int a = 0; a < 4; ++a)
#pragma unroll
    for (int b = 0; b < 4; ++b) acc[a][b] = (f32x4){0.f, 0.f, 0.f, 0.f};

  for (int kt = 0; kt < CC; kt += 64) {
    __syncthreads();
#pragma unroll
    for (int u = 0; u < 8; ++u) gld16(gsrc[u] + kt, ldst[u]);
    __syncthreads();
#pragma unroll
    for (int ks = 0; ks < 2; ++ks) {
      f16x8 af[4], bf[4];
#pragma unroll
      for (int mt = 0; mt < 4; ++mt)
        af[mt] = ldsR(sm, wm * 64 + mt * 16 + l15, ks * 4 + quad);
#pragma unroll
      for (int nt = 0; nt < 4; ++nt)
        bf[nt] = ldsR(sm + 8192, wn * 64 + nt * 16 + l15, ks * 4 + quad);
#pragma unroll
      for (int mt = 0; mt < 4; ++mt)
#pragma unroll
        for (int nt = 0; nt < 4; ++nt)
          acc[mt][nt] = __builtin_amdgcn_mfma_f32_16x16x32_f16(af[mt], bf[nt], acc[mt][nt], 0, 0, 0);
    }
  }

  const int sec = colblk / CC;                 // 0=q, 1=k, 2=v
  const int h   = ((colblk % CC) >> 6) + wn;
  float bv[4];
#pragma unroll
  for (int nt = 0; nt < 4; ++nt) bv[nt] = bias[colblk + wn * 64 + nt * 16 + l15];

  if (sec == 2) {
#pragma unroll
    for (int mt = 0; mt < 4; ++mt) {
      int rg0 = rowblk + wm * 64 + mt * 16 + quad * 4;
      int b = rg0 >> 10, n0 = rg0 & 1023;
#pragma unroll
      for (int nt = 0; nt < 4; ++nt) {
        int d = nt * 16 + l15;
        f16x4 pk;
#pragma unroll
        for (int i = 0; i < 4; ++i) pk[i] = (F16)(acc[mt][nt][i] + bv[nt]);
        *(f16x4*)(vt + ((size_t)(b * HH + h) * DH + d) * NN + n0) = pk;
      }
    }
  } else {
    const float inv = exp2f(-(float)l15 * 0.41524101186092029f);  // 100^(-l15/16)
#pragma unroll
    for (int mt = 0; mt < 4; ++mt) {
#pragma unroll
      for (int i = 0; i < 4; ++i) {
        int rg = rowblk + wm * 64 + mt * 16 + quad * 4 + i;
        int b = rg >> 10, n = rg & 1023;
        float a0 = acc[mt][0][i] + bv[0];
        float a1 = acc[mt][1][i] + bv[1];
        float a2 = acc[mt][2][i] + bv[2];
        float a3 = acc[mt][3][i] + bv[3];
        float r0 = a0, r1 = a1, r2 = a2, r3 = a3;
        if (n < num_img) {
          float py = (float)pos2d[((size_t)b * num_img + n) * 2 + 0];
          float px = (float)pos2d[((size_t)b * num_img + n) * 2 + 1];
          float sy, cy, sx, cx;
          __sincosf(py * inv, &sy, &cy);
          __sincosf(px * inv, &sx, &cx);
          r0 = a0 * cy - a1 * sy;
          r1 = a1 * cy + a0 * sy;
          r2 = a2 * cx - a3 * sx;
          r3 = a3 * cx + a2 * sx;
        }
        size_t idx = ((size_t)(b * HH + h) * NN + n) * DH + l15;
        if (sec == 0) {
          qh[idx]      = (F16)(r0 * 0.125f);
          qh[idx + 16] = (F16)(r1 * 0.125f);
          qh[idx + 32] = (F16)(r2 * 0.125f);
          qh[idx + 48] = (F16)(r3 * 0.125f);
        } else {
          kh[idx] = (F16)r0; kh[idx + 16] = (F16)r1;
          kh[idx + 32] = (F16)r2; kh[idx + 48] = (F16)r3;
        }
      }
    }
  }
}

// ---------------------------------------------------------------------------
// K4: out = AO @ W^T + b (fp16 in, fp32 out). M=8192 N=768 K=768.
// 128x64 tile, BK=64, XCD-panel swizzle.
// ---------------------------------------------------------------------------
__global__ __launch_bounds__(256)
void gemm_proj(const F16* __restrict__ AO, const F16* __restrict__ WP,
               const float* __restrict__ bias, float* __restrict__ out) {
  __shared__ alignas(16) F16 sm[8192 + 4096];  // AO 128x64 | W 64x64
  const int tid = threadIdx.x, lane = tid & 63, w = tid >> 6;
  const int wm = w & 1, wn = w >> 1;
  const int l15 = lane & 15, quad = lane >> 4;

  const int flat = blockIdx.y * 12 + blockIdx.x;
  const int xcd = flat & 7, g = flat >> 3;     // g in [0,96)
  const int colblk = (g % 12) * 64;
  const int rowblk = (xcd * 8 + g / 12) * 128;

  const int rloc = lane >> 3, ploc = lane & 7;
  const int cK = ploc ^ rloc;

  const F16* gsrc[6];
  F16* ldst[6];
#pragma unroll
  for (int u = 0; u < 6; ++u) {
    int t = w * 6 + u;                         // 24 loads: AO 16, W 8
    const F16* gb;
    int j;
    F16* lb;
    if (t < 16) { gb = AO + (size_t)rowblk * CC; j = t;      lb = sm; }
    else        { gb = WP + (size_t)colblk * CC; j = t - 16; lb = sm + 8192; }
    gsrc[u] = gb + (size_t)(8 * j + rloc) * CC + cK * 8;
    ldst[u] = lb + j * 512;
  }

  f32x4 acc[4][2];
#pragma unroll
  for (int a = 0; a < 4; ++a)
#pragma unroll
    for (int b = 0; b < 2; ++b) acc[a][b] = (f32x4){0.f, 0.f, 0.f, 0.f};

  for (int kt = 0; kt < CC; kt += 64) {
    __syncthreads();
#pragma unroll
    for (int u = 0; u < 6; ++u) gld16(gsrc[u] + kt, ldst[u]);
    __syncthreads();
#pragma unroll
    for (int ks = 0; ks < 2; ++ks) {
      f16x8 af[4], bf[2];
#pragma unroll
      for (int mt = 0; mt < 4; ++mt)
        af[mt] = ldsR(sm, wm * 64 + mt * 16 + l15, ks * 4 + quad);
#pragma unroll
      for (int nt = 0; nt < 2; ++nt)
        bf[nt] = ldsR(sm + 8192, wn * 32 + nt * 16 + l15, ks * 4 + quad);
#pragma unroll
      for (int mt = 0; mt < 4; ++mt)
#pragma unroll
        for (int nt = 0; nt < 2; ++nt)
          acc[mt][nt] = __builtin_amdgcn_mfma_f32_16x16x32_f16(af[mt], bf[nt], acc[mt][nt], 0, 0, 0);
    }
  }

#pragma unroll
  for (int nt = 0; nt < 2; ++nt) {
    int cg = colblk + wn * 32 + nt * 16 + l15;
    float bv = bias[cg];
#pragma unroll
    for (int mt = 0; mt < 4; ++mt)
#pragma unroll
      for (int i = 0; i < 4; ++i) {
        int rg = rowblk + wm * 64 + mt * 16 + quad * 4 + i;
        out[(size_t)rg * CC + cg] = acc[mt][nt][i] + bv;
      }
  }
}

// ---------------------------------------------------------------------------
// K3: MFMA flash attention, S^T form. 4 waves, 128 q/block, 128 keys/barrier
// (2 subtiles of 64). P C-layout -> B-layout via cross-quad shuffles (no LDS).
// ---------------------------------------------------------------------------
__global__ __launch_bounds__(256)
void attn_mfma(const F16* __restrict__ Qh, const F16* __restrict__ Kh,
               const F16* __restrict__ Vt, F16* __restrict__ AO) {
  __shared__ alignas(16) F16 Ks[2][4096];    // [subtile][key x d] swizzled
  __shared__ alignas(16) F16 Vs[2][4096];    // [subtile][d x kk] swizzled

  const int tid = threadIdx.x, lane = tid & 63, w = tid >> 6;
  const int l15 = lane & 15, quad = lane >> 4;

  // XCD swizzle: all 8 q-tiles of a bh on one XCD (K/V stays in that L2)
  const int flat = blockIdx.y * 8 + blockIdx.x;
  const int xcd = flat & 7, g = flat >> 3;    // g in [0,96)
  const int bh = xcd * 12 + g % 12;
  const int q0 = (g / 12) * 128 + w * 32;

  const size_t kqbase = (size_t)bh * NN * DH;
  const size_t vbase  = (size_t)bh * DH * NN;

  const int rloc = lane >> 3, ploc = lane & 7;
  const int cK = ploc ^ rloc;

  f16x8 qf[2][2];
#pragma unroll
  for (int qn = 0; qn < 2; ++qn)
#pragma unroll
    for (int st = 0; st < 2; ++st)
      qf[qn][st] = *(const f16x8*)(Qh + kqbase +
                    (size_t)(q0 + qn * 16 + l15) * DH + st * 32 + quad * 8);

  f32x4 o[2][4];
  float m_i[2], l_i[2];
#pragma unroll
  for (int qn = 0; qn < 2; ++qn) {
    m_i[qn] = -1e30f; l_i[qn] = 0.f;
#pragma unroll
    for (int gd = 0; gd < 4; ++gd) o[qn][gd] = (f32x4){0.f, 0.f, 0.f, 0.f};
  }

  for (int kt = 0; kt < NN; kt += 128) {
    __syncthreads();
    // wave w stages one 64x64 tile: w=0,1 -> Ks[0],Ks[1]; w=2,3 -> Vs[0],Vs[1]
    if (w < 2) {
#pragma unroll
      for (int j = 0; j < 8; ++j)
        gld16(Kh + kqbase + (size_t)(kt + w * 64 + 8 * j + rloc) * DH + cK * 8,
              Ks[w] + j * 512);
    } else {
#pragma unroll
      for (int j = 0; j < 8; ++j)
        gld16(Vt + vbase + (size_t)(8 * j + rloc) * NN + kt + (w - 2) * 64 + cK * 8,
              Vs[w - 2] + j * 512);
    }
    __syncthreads();

#pragma unroll
    for (int s = 0; s < 2; ++s) {
      f16x8 kf[4][2], vf[4][2];
#pragma unroll
      for (int gk = 0; gk < 4; ++gk)
#pragma unroll
        for (int st = 0; st < 2; ++st) {
          kf[gk][st] = ldsR(Ks[s], gk * 16 + l15, st * 4 + quad);
          vf[gk][st] = ldsR(Vs[s], gk * 16 + l15, st * 4 + quad);
        }

#pragma unroll
      for (int qn = 0; qn < 2; ++qn) {
        f32x4 sv[4];
#pragma unroll
        for (int gk = 0; gk < 4; ++gk) {
          sv[gk] = (f32x4){0.f, 0.f, 0.f, 0.f};
#pragma unroll
          for (int st = 0; st < 2; ++st)
            sv[gk] = __builtin_amdgcn_mfma_f32_16x16x32_f16(kf[gk][st], qf[qn][st], sv[gk], 0, 0, 0);
        }
        // online softmax: lane owns q = l15 (per qn), kk = gk*16+quad*4+i
        float rm = -1e30f;
#pragma unroll
        for (int gk = 0; gk < 4; ++gk)
#pragma unroll
          for (int i = 0; i < 4; ++i) rm = fmaxf(rm, sv[gk][i]);
        rm = fmaxf(rm, __shfl_xor(rm, 16, 64));
        rm = fmaxf(rm, __shfl_xor(rm, 32, 64));
        float mn = fmaxf(m_i[qn], rm);
        float alpha = __expf(m_i[qn] - mn);
        float rs = 0.f;
        union { f16x4 v; uint2 u; } pk[4];
#pragma unroll
        for (int gk = 0; gk < 4; ++gk)
#pragma unroll
          for (int i = 0; i < 4; ++i) {
            float p = __expf(sv[gk][i] - mn);
            rs += p;
            pk[gk].v[i] = (F16)p;
          }
        rs += __shfl_xor(rs, 16, 64);
        rs += __shfl_xor(rs, 32, 64);
        l_i[qn] = l_i[qn] * alpha + rs;
        m_i[qn] = mn;
#pragma unroll
        for (int gd = 0; gd < 4; ++gd) o[qn][gd] *= alpha;

        // C-layout -> B-layout: target (quad,j) needs kk=32st+8*quad+j,
        // i.e. pk[2st+(quad>>1)] from source quad 2*(quad&1)+(j>=4), same l15
        f16x8 pf[2];
        const int srcA = ((quad & 1) << 5) + l15;
#pragma unroll
        for (int st = 0; st < 2; ++st) {
          uint2 a0 = shfl_u2(pk[2 * st].u, srcA);
          uint2 b0 = shfl_u2(pk[2 * st + 1].u, srcA);
          uint2 a1 = shfl_u2(pk[2 * st].u, srcA + 16);
          uint2 b1 = shfl_u2(pk[2 * st + 1].u, srcA + 16);
          uint2 lo = (quad >> 1) ? b0 : a0;
          uint2 hi = (quad >> 1) ? b1 : a1;
          union { uint4 u; f16x8 v; } c;
          c.u = (uint4){lo.x, lo.y, hi.x, hi.y};
          pf[st] = c.v;
        }

        // O^T += V^T . P^T
#pragma unroll
        for (int gd = 0; gd < 4; ++gd) {
          o[qn][gd] = __builtin_amdgcn_mfma_f32_16x16x32_f16(vf[gd][0], pf[0], o[qn][gd], 0, 0, 0);
          o[qn][gd] = __builtin_amdgcn_mfma_f32_16x16x32_f16(vf[gd][1], pf[1], o[qn][gd], 0, 0, 0);
        }
      }
    }
  }

  // epilogue: O^T C-layout (d = gd*16+quad*4+i, q = qn*16+l15) -> AO fp16
  const int b = bh / HH, h = bh % HH;
#pragma unroll
  for (int qn = 0; qn < 2; ++qn) {
    float invl = 1.0f / l_i[qn];
    int n = q0 + qn * 16 + l15;
#pragma unroll
    for (int gd = 0; gd < 4; ++gd) {
      f16x4 hv;
#pragma unroll
      for (int i = 0; i < 4; ++i) hv[i] = (F16)(o[qn][gd][i] * invl);
      size_t idx = ((size_t)(b * NN + n)) * CC + h * DH + gd * 16 + quad * 4;
      *(f16x4*)(AO + idx) = hv;
    }
  }
}

// ---------------------------------------------------------------------------
extern "C" void kernel_launch(void* const* d_in, const int* in_sizes, int n_in,
                              void* d_out, int out_size, void* d_ws, size_t ws_size,
                              hipStream_t stream) {
  const float* x      = (const float*)d_in[0];
  const float* qkv_w  = (const float*)d_in[1];
  const float* qkv_b  = (const float*)d_in[2];
  const float* proj_w = (const float*)d_in[3];
  const float* proj_b = (const float*)d_in[4];
  const int*   pos2d  = (const int*)d_in[5];
  const int num_img = in_sizes[5] / (2 * BB);

  char* ws = (char*)d_ws;
  F16* x_h  = (F16*)(ws + 0);             // 12,582,912 B
  F16* wq_h = (F16*)(ws + 12582912);      // 3,538,944 B
  F16* wp_h = (F16*)(ws + 16121856);      // 1,179,648 B
  F16* q_h  = (F16*)(ws + 17301504);      // 12,582,912 B each
  F16* k_h  = (F16*)(ws + 29884416);
  F16* vt   = (F16*)(ws + 42467328);      // V transposed [b,h,d,n]
  F16* ao_h = (F16*)(ws + 55050240);      // end 67,633,152 B
  float* out = (float*)d_out;

  convert_all<<<(NX4 + NW1 + NW2 + 255) / 256, 256, 0, stream>>>(
      x, qkv_w, proj_w, x_h, wq_h, wp_h);

  gemm_qkv_rope<<<dim3(QKV3 / 128, (BB * NN) / 128), 256, 0, stream>>>(
      x_h, wq_h, qkv_b, pos2d, q_h, k_h, vt, num_img);

  attn_mfma<<<dim3(NN / 128, BB * HH), 256, 0, stream>>>(
      q_h, k_h, vt, ao_h);

  gemm_proj<<<dim3(CC / 64, (BB * NN) / 128), 256, 0, stream>>>(
      ao_h, wp_h, proj_b, out);
}

// Round 6
// 215.582 us; speedup vs baseline: 4.7184x; 1.0217x over previous
//
#include <hip/hip_runtime.h>
#include <math.h>

typedef _Float16 F16;
typedef _Float16 f16x8 __attribute__((ext_vector_type(8)));
typedef _Float16 f16x4 __attribute__((ext_vector_type(4)));
typedef float f32x4 __attribute__((ext_vector_type(4)));

#define BB 8
#define NN 1024
#define CC 768
#define HH 12
#define DH 64
#define QKV3 2304

// async global->LDS, 16B/lane; LDS dest = wave-uniform base + lane*16
__device__ __forceinline__ void gld16(const F16* g, F16* l) {
  __builtin_amdgcn_global_load_lds(
      (const __attribute__((address_space(1))) void*)g,
      (__attribute__((address_space(3))) void*)l, 16, 0, 0);
}

// f16x8 from 128B-row swizzled LDS: row m (64 halfs), global chunk cc at cc^(m&7)
__device__ __forceinline__ f16x8 ldsR(const F16* base, int m, int cc) {
  return *(const f16x8*)(base + (m << 6) + ((cc ^ (m & 7)) << 3));
}
// f16x4 from swizzled LDS: row m, global chunk c, byte-sub-offset off halfs
__device__ __forceinline__ f16x4 ldsV4(const F16* base, int m, int c, int off) {
  return *(const f16x4*)(base + (m << 6) + ((c ^ (m & 7)) << 3) + off);
}

// ---------------------------------------------------------------------------
// Converters: qkv_w, proj_w -> fp16 (x conversion is fused into K1)
// ---------------------------------------------------------------------------
#define NW1 442368    // 2304*768/4
#define NW2 147456    // 768*768/4
__global__ __launch_bounds__(256)
void convert_w(const float* __restrict__ w1, const float* __restrict__ w2,
               F16* __restrict__ w1h, F16* __restrict__ w2h) {
  int i = blockIdx.x * 256 + threadIdx.x;
  if (i < NW1) {
    float4 v = ((const float4*)w1)[i];
    f16x4 h = {(F16)v.x, (F16)v.y, (F16)v.z, (F16)v.w};
    ((f16x4*)w1h)[i] = h;
  } else if (i < NW1 + NW2) {
    int j = i - NW1;
    float4 v = ((const float4*)w2)[j];
    f16x4 h = {(F16)v.x, (F16)v.y, (F16)v.z, (F16)v.w};
    ((f16x4*)w2h)[j] = h;
  }
}

// ---------------------------------------------------------------------------
// K1: QKV GEMM (x fp32 cast in staging, W fp16) + fused RoPE2D epilogue.
// M=8192 N=2304 K=768. 128x128 tile, BK=64, XCD-panel swizzle.
// ---------------------------------------------------------------------------
__global__ __launch_bounds__(256)
void gemm_qkv_rope(const float* __restrict__ X, const F16* __restrict__ WQ,
                   const float* __restrict__ bias, const int* __restrict__ pos2d,
                   F16* __restrict__ qh, F16* __restrict__ kh,
                   F16* __restrict__ vt, int num_img) {
  __shared__ alignas(16) F16 sm[2 * 8192];   // X tile | W tile, 16KB each
  const int tid = threadIdx.x, lane = tid & 63, w = tid >> 6;
  const int wm = w & 1, wn = w >> 1;
  const int l15 = lane & 15, quad = lane >> 4;

  // XCD-panel swizzle: each XCD owns 8 row-stripes x all 18 col-blocks
  const int flat = blockIdx.y * 18 + blockIdx.x;
  const int xcd = flat & 7, g = flat >> 3;     // g in [0,144)
  const int colblk = (g % 18) * 128;
  const int rowblk = (xcd * 8 + g / 18) * 128;

  const int rloc = lane >> 3, ploc = lane & 7;
  const int cK = ploc ^ rloc;                  // swizzled global chunk

  const float* xsrc[4];
  F16* adst[4];
  const F16* wsrc[4];
  F16* wdst[4];
#pragma unroll
  for (int u = 0; u < 4; ++u) {
    int j = w * 4 + u;                         // 16 j-blocks each for A and W
    xsrc[u] = X + (size_t)(rowblk + 8 * j + rloc) * CC + cK * 8;
    adst[u] = sm + j * 512 + lane * 8;
    wsrc[u] = WQ + (size_t)(colblk + 8 * j + rloc) * CC + cK * 8;
    wdst[u] = sm + 8192 + j * 512;
  }

  f32x4 acc[4][4];
#pragma unroll
  for (int a = 0; a < 4; ++a)
#pragma unroll
    for (int b = 0; b < 4; ++b) acc[a][b] = (f32x4){0.f, 0.f, 0.f, 0.f};

  for (int kt = 0; kt < CC; kt += 64) {
    __syncthreads();
#pragma unroll
    for (int u = 0; u < 4; ++u) gld16(wsrc[u] + kt, wdst[u]);   // async W
#pragma unroll
    for (int u = 0; u < 4; ++u) {                               // manual A+cvt
      float4 f0 = *(const float4*)(xsrc[u] + kt);
      float4 f1 = *(const float4*)(xsrc[u] + kt + 4);
      f16x8 h;
      h[0] = (F16)f0.x; h[1] = (F16)f0.y; h[2] = (F16)f0.z; h[3] = (F16)f0.w;
      h[4] = (F16)f1.x; h[5] = (F16)f1.y; h[6] = (F16)f1.z; h[7] = (F16)f1.w;
      *(f16x8*)adst[u] = h;
    }
    __syncthreads();
#pragma unroll
    for (int ks = 0; ks < 2; ++ks) {
      f16x8 af[4], bf[4];
#pragma unroll
      for (int mt = 0; mt < 4; ++mt)
        af[mt] = ldsR(sm, wm * 64 + mt * 16 + l15, ks * 4 + quad);
#pragma unroll
      for (int nt = 0; nt < 4; ++nt)
        bf[nt] = ldsR(sm + 8192, wn * 64 + nt * 16 + l15, ks * 4 + quad);
#pragma unroll
      for (int mt = 0; mt < 4; ++mt)
#pragma unroll
        for (int nt = 0; nt < 4; ++nt)
          acc[mt][nt] = __builtin_amdgcn_mfma_f32_16x16x32_f16(af[mt], bf[nt], acc[mt][nt], 0, 0, 0);
    }
  }

  const int sec = colblk / CC;                 // 0=q, 1=k, 2=v
  const int h   = ((colblk % CC) >> 6) + wn;
  float bv[4];
#pragma unroll
  for (int nt = 0; nt < 4; ++nt) bv[nt] = bias[colblk + wn * 64 + nt * 16 + l15];

  if (sec == 2) {
#pragma unroll
    for (int mt = 0; mt < 4; ++mt) {
      int rg0 = rowblk + wm * 64 + mt * 16 + quad * 4;
      int b = rg0 >> 10, n0 = rg0 & 1023;
#pragma unroll
      for (int nt = 0; nt < 4; ++nt) {
        int d = nt * 16 + l15;
        f16x4 pk;
#pragma unroll
        for (int i = 0; i < 4; ++i) pk[i] = (F16)(acc[mt][nt][i] + bv[nt]);
        *(f16x4*)(vt + ((size_t)(b * HH + h) * DH + d) * NN + n0) = pk;
      }
    }
  } else {
    const float inv = exp2f(-(float)l15 * 0.41524101186092029f);  // 100^(-l15/16)
#pragma unroll
    for (int mt = 0; mt < 4; ++mt) {
#pragma unroll
      for (int i = 0; i < 4; ++i) {
        int rg = rowblk + wm * 64 + mt * 16 + quad * 4 + i;
        int b = rg >> 10, n = rg & 1023;
        float a0 = acc[mt][0][i] + bv[0];
        float a1 = acc[mt][1][i] + bv[1];
        float a2 = acc[mt][2][i] + bv[2];
        float a3 = acc[mt][3][i] + bv[3];
        float r0 = a0, r1 = a1, r2 = a2, r3 = a3;
        if (n < num_img) {
          float py = (float)pos2d[((size_t)b * num_img + n) * 2 + 0];
          float px = (float)pos2d[((size_t)b * num_img + n) * 2 + 1];
          float sy, cy, sx, cx;
          __sincosf(py * inv, &sy, &cy);
          __sincosf(px * inv, &sx, &cx);
          r0 = a0 * cy - a1 * sy;
          r1 = a1 * cy + a0 * sy;
          r2 = a2 * cx - a3 * sx;
          r3 = a3 * cx + a2 * sx;
        }
        size_t idx = ((size_t)(b * HH + h) * NN + n) * DH + l15;
        if (sec == 0) {
          qh[idx]      = (F16)(r0 * 0.125f);
          qh[idx + 16] = (F16)(r1 * 0.125f);
          qh[idx + 32] = (F16)(r2 * 0.125f);
          qh[idx + 48] = (F16)(r3 * 0.125f);
        } else {
          kh[idx] = (F16)r0; kh[idx + 16] = (F16)r1;
          kh[idx + 32] = (F16)r2; kh[idx + 48] = (F16)r3;
        }
      }
    }
  }
}

// ---------------------------------------------------------------------------
// K4: out = AO @ W^T + b (fp16 in, fp32 out). M=8192 N=768 K=768.
// 128x64 tile, BK=64, XCD-panel swizzle.
// ---------------------------------------------------------------------------
__global__ __launch_bounds__(256)
void gemm_proj(const F16* __restrict__ AO, const F16* __restrict__ WP,
               const float* __restrict__ bias, float* __restrict__ out) {
  __shared__ alignas(16) F16 sm[8192 + 4096];  // AO 128x64 | W 64x64
  const int tid = threadIdx.x, lane = tid & 63, w = tid >> 6;
  const int wm = w & 1, wn = w >> 1;
  const int l15 = lane & 15, quad = lane >> 4;

  const int flat = blockIdx.y * 12 + blockIdx.x;
  const int xcd = flat & 7, g = flat >> 3;     // g in [0,96)
  const int colblk = (g % 12) * 64;
  const int rowblk = (xcd * 8 + g / 12) * 128;

  const int rloc = lane >> 3, ploc = lane & 7;
  const int cK = ploc ^ rloc;

  const F16* gsrc[6];
  F16* ldst[6];
#pragma unroll
  for (int u = 0; u < 6; ++u) {
    int t = w * 6 + u;                         // 24 loads: AO 16, W 8
    const F16* gb;
    int j;
    F16* lb;
    if (t < 16) { gb = AO + (size_t)rowblk * CC; j = t;      lb = sm; }
    else        { gb = WP + (size_t)colblk * CC; j = t - 16; lb = sm + 8192; }
    gsrc[u] = gb + (size_t)(8 * j + rloc) * CC + cK * 8;
    ldst[u] = lb + j * 512;
  }

  f32x4 acc[4][2];
#pragma unroll
  for (int a = 0; a < 4; ++a)
#pragma unroll
    for (int b = 0; b < 2; ++b) acc[a][b] = (f32x4){0.f, 0.f, 0.f, 0.f};

  for (int kt = 0; kt < CC; kt += 64) {
    __syncthreads();
#pragma unroll
    for (int u = 0; u < 6; ++u) gld16(gsrc[u] + kt, ldst[u]);
    __syncthreads();
#pragma unroll
    for (int ks = 0; ks < 2; ++ks) {
      f16x8 af[4], bf[2];
#pragma unroll
      for (int mt = 0; mt < 4; ++mt)
        af[mt] = ldsR(sm, wm * 64 + mt * 16 + l15, ks * 4 + quad);
#pragma unroll
      for (int nt = 0; nt < 2; ++nt)
        bf[nt] = ldsR(sm + 8192, wn * 32 + nt * 16 + l15, ks * 4 + quad);
#pragma unroll
      for (int mt = 0; mt < 4; ++mt)
#pragma unroll
        for (int nt = 0; nt < 2; ++nt)
          acc[mt][nt] = __builtin_amdgcn_mfma_f32_16x16x32_f16(af[mt], bf[nt], acc[mt][nt], 0, 0, 0);
    }
  }

#pragma unroll
  for (int nt = 0; nt < 2; ++nt) {
    int cg = colblk + wn * 32 + nt * 16 + l15;
    float bv = bias[cg];
#pragma unroll
    for (int mt = 0; mt < 4; ++mt)
#pragma unroll
      for (int i = 0; i < 4; ++i) {
        int rg = rowblk + wm * 64 + mt * 16 + quad * 4 + i;
        out[(size_t)rg * CC + cg] = acc[mt][nt][i] + bv;
      }
  }
}

// ---------------------------------------------------------------------------
// K3: MFMA flash attention, S^T form. 4 waves, 128 q/block, 128 keys per
// barrier; ONE softmax pass per 128 keys; PV via K=16 MFMA consuming P in
// C-layout directly (B-operand of 16x16x16 == C-layout of S^T) — no
// transpose shuffles at all.
// ---------------------------------------------------------------------------
__global__ __launch_bounds__(256)
void attn_mfma(const F16* __restrict__ Qh, const F16* __restrict__ Kh,
               const F16* __restrict__ Vt, F16* __restrict__ AO) {
  __shared__ alignas(16) F16 Ks[2][4096];    // [subtile][key x d] swizzled
  __shared__ alignas(16) F16 Vs[2][4096];    // [subtile][d x kk] swizzled

  const int tid = threadIdx.x, lane = tid & 63, w = tid >> 6;
  const int l15 = lane & 15, quad = lane >> 4;

  // XCD swizzle: all 8 q-tiles of a bh on one XCD (K/V stays in that L2)
  const int flat = blockIdx.y * 8 + blockIdx.x;
  const int xcd = flat & 7, g = flat >> 3;    // g in [0,96)
  const int bh = xcd * 12 + g % 12;
  const int q0 = (g / 12) * 128 + w * 32;

  const size_t kqbase = (size_t)bh * NN * DH;
  const size_t vbase  = (size_t)bh * DH * NN;

  const int rloc = lane >> 3, ploc = lane & 7;
  const int cK = ploc ^ rloc;

  f16x8 qf[2][2];
#pragma unroll
  for (int qn = 0; qn < 2; ++qn)
#pragma unroll
    for (int st = 0; st < 2; ++st)
      qf[qn][st] = *(const f16x8*)(Qh + kqbase +
                    (size_t)(q0 + qn * 16 + l15) * DH + st * 32 + quad * 8);

  f32x4 o[2][4];
  float m_i[2], l_i[2];
#pragma unroll
  for (int qn = 0; qn < 2; ++qn) {
    m_i[qn] = -1e30f; l_i[qn] = 0.f;
#pragma unroll
    for (int gd = 0; gd < 4; ++gd) o[qn][gd] = (f32x4){0.f, 0.f, 0.f, 0.f};
  }

  for (int kt = 0; kt < NN; kt += 128) {
    __syncthreads();
    // wave w stages one 64x64 tile: w=0,1 -> Ks[0],Ks[1]; w=2,3 -> Vs[0],Vs[1]
    if (w < 2) {
#pragma unroll
      for (int j = 0; j < 8; ++j)
        gld16(Kh + kqbase + (size_t)(kt + w * 64 + 8 * j + rloc) * DH + cK * 8,
              Ks[w] + j * 512);
    } else {
#pragma unroll
      for (int j = 0; j < 8; ++j)
        gld16(Vt + vbase + (size_t)(8 * j + rloc) * NN + kt + (w - 2) * 64 + cK * 8,
              Vs[w - 2] + j * 512);
    }
    __syncthreads();

    // scores for all 128 keys, both qn (grp: sub = grp>>2, local gk = grp&3)
    f32x4 s[2][8];
#pragma unroll
    for (int grp = 0; grp < 8; ++grp) {
      const F16* kb = Ks[grp >> 2];
      int m = (grp & 3) * 16 + l15;
      f16x8 kf0 = ldsR(kb, m, quad);
      f16x8 kf1 = ldsR(kb, m, 4 + quad);
#pragma unroll
      for (int qn = 0; qn < 2; ++qn) {
        f32x4 t = (f32x4){0.f, 0.f, 0.f, 0.f};
        t = __builtin_amdgcn_mfma_f32_16x16x32_f16(kf0, qf[qn][0], t, 0, 0, 0);
        t = __builtin_amdgcn_mfma_f32_16x16x32_f16(kf1, qf[qn][1], t, 0, 0, 0);
        s[qn][grp] = t;
      }
    }

    // one online-softmax pass per qn over all 128 keys
    f16x4 pk[2][8];
#pragma unroll
    for (int qn = 0; qn < 2; ++qn) {
      float rm = -1e30f;
#pragma unroll
      for (int grp = 0; grp < 8; ++grp)
#pragma unroll
        for (int i = 0; i < 4; ++i) rm = fmaxf(rm, s[qn][grp][i]);
      rm = fmaxf(rm, __shfl_xor(rm, 16, 64));
      rm = fmaxf(rm, __shfl_xor(rm, 32, 64));
      float mn = fmaxf(m_i[qn], rm);
      float alpha = __expf(m_i[qn] - mn);
      float rs = 0.f;
#pragma unroll
      for (int grp = 0; grp < 8; ++grp)
#pragma unroll
        for (int i = 0; i < 4; ++i) {
          float p = __expf(s[qn][grp][i] - mn);
          rs += p;
          pk[qn][grp][i] = (F16)p;
        }
      rs += __shfl_xor(rs, 16, 64);
      rs += __shfl_xor(rs, 32, 64);
      l_i[qn] = l_i[qn] * alpha + rs;
      m_i[qn] = mn;
#pragma unroll
      for (int gd = 0; gd < 4; ++gd) o[qn][gd] *= alpha;
    }

    // PV: K=16 MFMA, P consumed directly in C-layout (kk = grp*16+quad*4+i)
#pragma unroll
    for (int grp = 0; grp < 8; ++grp) {
      const F16* vb = Vs[grp >> 2];
      int c2 = ((grp & 3) << 1) + (quad >> 1);
      int off = (quad & 1) * 4;
#pragma unroll
      for (int gd = 0; gd < 4; ++gd) {
        f16x4 vf = ldsV4(vb, gd * 16 + l15, c2, off);
        o[0][gd] = __builtin_amdgcn_mfma_f32_16x16x16f16(vf, pk[0][grp], o[0][gd], 0, 0, 0);
        o[1][gd] = __builtin_amdgcn_mfma_f32_16x16x16f16(vf, pk[1][grp], o[1][gd], 0, 0, 0);
      }
    }
  }

  // epilogue: O^T C-layout (d = gd*16+quad*4+i, q = qn*16+l15) -> AO fp16
  const int b = bh / HH, h = bh % HH;
#pragma unroll
  for (int qn = 0; qn < 2; ++qn) {
    float invl = 1.0f / l_i[qn];
    int n = q0 + qn * 16 + l15;
#pragma unroll
    for (int gd = 0; gd < 4; ++gd) {
      f16x4 hv;
#pragma unroll
      for (int i = 0; i < 4; ++i) hv[i] = (F16)(o[qn][gd][i] * invl);
      size_t idx = ((size_t)(b * NN + n)) * CC + h * DH + gd * 16 + quad * 4;
      *(f16x4*)(AO + idx) = hv;
    }
  }
}

// ---------------------------------------------------------------------------
extern "C" void kernel_launch(void* const* d_in, const int* in_sizes, int n_in,
                              void* d_out, int out_size, void* d_ws, size_t ws_size,
                              hipStream_t stream) {
  const float* x      = (const float*)d_in[0];
  const float* qkv_w  = (const float*)d_in[1];
  const float* qkv_b  = (const float*)d_in[2];
  const float* proj_w = (const float*)d_in[3];
  const float* proj_b = (const float*)d_in[4];
  const int*   pos2d  = (const int*)d_in[5];
  const int num_img = in_sizes[5] / (2 * BB);

  char* ws = (char*)d_ws;
  F16* wq_h = (F16*)(ws + 0);             // 3,538,944 B
  F16* wp_h = (F16*)(ws + 3538944);       // 1,179,648 B
  F16* q_h  = (F16*)(ws + 4718592);       // 12,582,912 B each
  F16* k_h  = (F16*)(ws + 17301504);
  F16* vt   = (F16*)(ws + 29884416);      // V transposed [b,h,d,n]
  F16* ao_h = (F16*)(ws + 42467328);      // end 55,050,240 B
  float* out = (float*)d_out;

  convert_w<<<(NW1 + NW2 + 255) / 256, 256, 0, stream>>>(qkv_w, proj_w, wq_h, wp_h);

  gemm_qkv_rope<<<dim3(QKV3 / 128, (BB * NN) / 128), 256, 0, stream>>>(
      x, wq_h, qkv_b, pos2d, q_h, k_h, vt, num_img);

  attn_mfma<<<dim3(NN / 128, BB * HH), 256, 0, stream>>>(
      q_h, k_h, vt, ao_h);

  gemm_proj<<<dim3(CC / 64, (BB * NN) / 128), 256, 0, stream>>>(
      ao_h, wp_h, proj_b, out);
}

// Round 7
// 212.023 us; speedup vs baseline: 4.7976x; 1.0168x over previous
//
#include <hip/hip_runtime.h>
#include <math.h>

typedef _Float16 F16;
typedef _Float16 f16x8 __attribute__((ext_vector_type(8)));
typedef _Float16 f16x4 __attribute__((ext_vector_type(4)));
typedef float f32x4 __attribute__((ext_vector_type(4)));

#define BB 8
#define NN 1024
#define CC 768
#define HH 12
#define DH 64
#define QKV3 2304

// async global->LDS, 16B/lane; LDS dest = wave-uniform base + lane*16
__device__ __forceinline__ void gld16(const F16* g, F16* l) {
  __builtin_amdgcn_global_load_lds(
      (const __attribute__((address_space(1))) void*)g,
      (__attribute__((address_space(3))) void*)l, 16, 0, 0);
}

// f16x8 from 128B-row swizzled LDS: row m (64 halfs), global chunk cc at cc^(m&7)
__device__ __forceinline__ f16x8 ldsR(const F16* base, int m, int cc) {
  return *(const f16x8*)(base + (m << 6) + ((cc ^ (m & 7)) << 3));
}
// f16x4 from swizzled LDS: row m, global chunk c, sub-offset off halfs
__device__ __forceinline__ f16x4 ldsV4(const F16* base, int m, int c, int off) {
  return *(const f16x4*)(base + (m << 6) + ((c ^ (m & 7)) << 3) + off);
}

// ---------------------------------------------------------------------------
// Converters: qkv_w, proj_w -> fp16
// ---------------------------------------------------------------------------
#define NW1 442368    // 2304*768/4
#define NW2 147456    // 768*768/4
__global__ __launch_bounds__(256)
void convert_w(const float* __restrict__ w1, const float* __restrict__ w2,
               F16* __restrict__ w1h, F16* __restrict__ w2h) {
  int i = blockIdx.x * 256 + threadIdx.x;
  if (i < NW1) {
    float4 v = ((const float4*)w1)[i];
    f16x4 h = {(F16)v.x, (F16)v.y, (F16)v.z, (F16)v.w};
    ((f16x4*)w1h)[i] = h;
  } else if (i < NW1 + NW2) {
    int j = i - NW1;
    float4 v = ((const float4*)w2)[j];
    f16x4 h = {(F16)v.x, (F16)v.y, (F16)v.z, (F16)v.w};
    ((f16x4*)w2h)[j] = h;
  }
}

// ---------------------------------------------------------------------------
// K1: QKV GEMM (x fp32 cast in staging, W fp16 gld16 double-buffered) +
// fused RoPE2D epilogue. M=8192 N=2304 K=768. 128x128 tile, BK=64.
// X(k+1) VGPR-prefetch + W(k+1) gld16 issued AFTER barrier-2 -> fly during
// MFMA(k), drained at barrier-1(k+1). LDS 48 KB.
// ---------------------------------------------------------------------------
__global__ __launch_bounds__(256)
void gemm_qkv_rope(const float* __restrict__ X, const F16* __restrict__ WQ,
                   const float* __restrict__ bias, const int* __restrict__ pos2d,
                   F16* __restrict__ qh, F16* __restrict__ kh,
                   F16* __restrict__ vt, int num_img) {
  __shared__ alignas(16) F16 sm[8192 + 2 * 8192];   // A | W0 | W1
  const int tid = threadIdx.x, lane = tid & 63, w = tid >> 6;
  const int wm = w & 1, wn = w >> 1;
  const int l15 = lane & 15, quad = lane >> 4;

  // XCD-panel swizzle
  const int flat = blockIdx.y * 18 + blockIdx.x;
  const int xcd = flat & 7, g = flat >> 3;
  const int colblk = (g % 18) * 128;
  const int rowblk = (xcd * 8 + g / 18) * 128;

  const int rloc = lane >> 3, ploc = lane & 7;
  const int cK = ploc ^ rloc;

  const float* xsrc[4];
  F16* adst[4];
  const F16* wsrc[4];
  int woff[4];
#pragma unroll
  for (int u = 0; u < 4; ++u) {
    int j = w * 4 + u;
    xsrc[u] = X + (size_t)(rowblk + 8 * j + rloc) * CC + cK * 8;
    adst[u] = sm + j * 512 + lane * 8;
    wsrc[u] = WQ + (size_t)(colblk + 8 * j + rloc) * CC + cK * 8;
    woff[u] = j * 512;
  }

  // prologue: W(0) async, X(0) to regs
#pragma unroll
  for (int u = 0; u < 4; ++u) gld16(wsrc[u], sm + 8192 + woff[u]);
  float4 xr[4][2];
#pragma unroll
  for (int u = 0; u < 4; ++u) {
    xr[u][0] = *(const float4*)(xsrc[u]);
    xr[u][1] = *(const float4*)(xsrc[u] + 4);
  }

  f32x4 acc[4][4];
#pragma unroll
  for (int a = 0; a < 4; ++a)
#pragma unroll
    for (int b = 0; b < 4; ++b) acc[a][b] = (f32x4){0.f, 0.f, 0.f, 0.f};

#pragma unroll 1
  for (int it = 0; it < 12; ++it) {
    __syncthreads();                    // barrier 1: A-LDS free, drains prefetch
#pragma unroll
    for (int u = 0; u < 4; ++u) {      // cvt + stage A(it)
      f16x8 h;
      h[0] = (F16)xr[u][0].x; h[1] = (F16)xr[u][0].y;
      h[2] = (F16)xr[u][0].z; h[3] = (F16)xr[u][0].w;
      h[4] = (F16)xr[u][1].x; h[5] = (F16)xr[u][1].y;
      h[6] = (F16)xr[u][1].z; h[7] = (F16)xr[u][1].w;
      *(f16x8*)adst[u] = h;
    }
    __syncthreads();                    // barrier 2: cheap (LDS only)

    if (it < 11) {                      // prefetch (it+1): flies during MFMA(it)
      int kt2 = (it + 1) * 64;
      F16* wb = sm + 8192 + ((it + 1) & 1) * 8192;
#pragma unroll
      for (int u = 0; u < 4; ++u) gld16(wsrc[u] + kt2, wb + woff[u]);
#pragma unroll
      for (int u = 0; u < 4; ++u) {
        xr[u][0] = *(const float4*)(xsrc[u] + kt2);
        xr[u][1] = *(const float4*)(xsrc[u] + kt2 + 4);
      }
    }

    const F16* wbase = sm + 8192 + (it & 1) * 8192;
#pragma unroll
    for (int ks = 0; ks < 2; ++ks) {
      f16x8 af[4], bf[4];
#pragma unroll
      for (int mt = 0; mt < 4; ++mt)
        af[mt] = ldsR(sm, wm * 64 + mt * 16 + l15, ks * 4 + quad);
#pragma unroll
      for (int nt = 0; nt < 4; ++nt)
        bf[nt] = ldsR(wbase, wn * 64 + nt * 16 + l15, ks * 4 + quad);
#pragma unroll
      for (int mt = 0; mt < 4; ++mt)
#pragma unroll
        for (int nt = 0; nt < 4; ++nt)
          acc[mt][nt] = __builtin_amdgcn_mfma_f32_16x16x32_f16(af[mt], bf[nt], acc[mt][nt], 0, 0, 0);
    }
  }

  const int sec = colblk / CC;                 // 0=q, 1=k, 2=v
  const int h   = ((colblk % CC) >> 6) + wn;
  float bv[4];
#pragma unroll
  for (int nt = 0; nt < 4; ++nt) bv[nt] = bias[colblk + wn * 64 + nt * 16 + l15];

  if (sec == 2) {
#pragma unroll
    for (int mt = 0; mt < 4; ++mt) {
      int rg0 = rowblk + wm * 64 + mt * 16 + quad * 4;
      int b = rg0 >> 10, n0 = rg0 & 1023;
#pragma unroll
      for (int nt = 0; nt < 4; ++nt) {
        int d = nt * 16 + l15;
        f16x4 pk;
#pragma unroll
        for (int i = 0; i < 4; ++i) pk[i] = (F16)(acc[mt][nt][i] + bv[nt]);
        *(f16x4*)(vt + ((size_t)(b * HH + h) * DH + d) * NN + n0) = pk;
      }
    }
  } else {
    const float inv = exp2f(-(float)l15 * 0.41524101186092029f);  // 100^(-l15/16)
#pragma unroll
    for (int mt = 0; mt < 4; ++mt) {
#pragma unroll
      for (int i = 0; i < 4; ++i) {
        int rg = rowblk + wm * 64 + mt * 16 + quad * 4 + i;
        int b = rg >> 10, n = rg & 1023;
        float a0 = acc[mt][0][i] + bv[0];
        float a1 = acc[mt][1][i] + bv[1];
        float a2 = acc[mt][2][i] + bv[2];
        float a3 = acc[mt][3][i] + bv[3];
        float r0 = a0, r1 = a1, r2 = a2, r3 = a3;
        if (n < num_img) {
          float py = (float)pos2d[((size_t)b * num_img + n) * 2 + 0];
          float px = (float)pos2d[((size_t)b * num_img + n) * 2 + 1];
          float sy, cy, sx, cx;
          __sincosf(py * inv, &sy, &cy);
          __sincosf(px * inv, &sx, &cx);
          r0 = a0 * cy - a1 * sy;
          r1 = a1 * cy + a0 * sy;
          r2 = a2 * cx - a3 * sx;
          r3 = a3 * cx + a2 * sx;
        }
        size_t idx = ((size_t)(b * HH + h) * NN + n) * DH + l15;
        if (sec == 0) {
          qh[idx]      = (F16)(r0 * 0.125f);
          qh[idx + 16] = (F16)(r1 * 0.125f);
          qh[idx + 32] = (F16)(r2 * 0.125f);
          qh[idx + 48] = (F16)(r3 * 0.125f);
        } else {
          kh[idx] = (F16)r0; kh[idx + 16] = (F16)r1;
          kh[idx + 32] = (F16)r2; kh[idx + 48] = (F16)r3;
        }
      }
    }
  }
}

// ---------------------------------------------------------------------------
// K4: out = AO @ W^T + b. M=8192 N=768 K=768. 128x64 tile, BK=64.
// Full double-buffer (A 2x16KB, W 2x8KB) -> ONE barrier per iter; gld16(k+1)
// issued right after the barrier, hidden behind MFMA(k).
// ---------------------------------------------------------------------------
__global__ __launch_bounds__(256)
void gemm_proj(const F16* __restrict__ AO, const F16* __restrict__ WP,
               const float* __restrict__ bias, float* __restrict__ out) {
  __shared__ alignas(16) F16 sm[2 * 8192 + 2 * 4096];  // A0 A1 W0 W1
  const int tid = threadIdx.x, lane = tid & 63, w = tid >> 6;
  const int wm = w & 1, wn = w >> 1;
  const int l15 = lane & 15, quad = lane >> 4;

  const int flat = blockIdx.y * 12 + blockIdx.x;
  const int xcd = flat & 7, g = flat >> 3;
  const int colblk = (g % 12) * 64;
  const int rowblk = (xcd * 8 + g / 12) * 128;

  const int rloc = lane >> 3, ploc = lane & 7;
  const int cK = ploc ^ rloc;

  const F16* gsrc[6];
  F16* ldst0[6];
  F16* ldst1[6];
#pragma unroll
  for (int u = 0; u < 6; ++u) {
    int t = w * 6 + u;                         // 24 loads: AO 16, W 8
    if (t < 16) {
      gsrc[u]  = AO + (size_t)(rowblk + 8 * t + rloc) * CC + cK * 8;
      ldst0[u] = sm + t * 512;
      ldst1[u] = sm + 8192 + t * 512;
    } else {
      int j = t - 16;
      gsrc[u]  = WP + (size_t)(colblk + 8 * j + rloc) * CC + cK * 8;
      ldst0[u] = sm + 16384 + j * 512;
      ldst1[u] = sm + 16384 + 4096 + j * 512;
    }
  }

  // prologue: stage iter 0 into buffer 0
#pragma unroll
  for (int u = 0; u < 6; ++u) gld16(gsrc[u], ldst0[u]);

  f32x4 acc[4][2];
#pragma unroll
  for (int a = 0; a < 4; ++a)
#pragma unroll
    for (int b = 0; b < 2; ++b) acc[a][b] = (f32x4){0.f, 0.f, 0.f, 0.f};

#pragma unroll 1
  for (int it = 0; it < 12; ++it) {
    __syncthreads();   // drains gld16(it); all waves done reading buf[(it+1)&1]
    if (it < 11) {
      int kt2 = (it + 1) * 64;
      if ((it + 1) & 1) {
#pragma unroll
        for (int u = 0; u < 6; ++u) gld16(gsrc[u] + kt2, ldst1[u]);
      } else {
#pragma unroll
        for (int u = 0; u < 6; ++u) gld16(gsrc[u] + kt2, ldst0[u]);
      }
    }
    const F16* abase = sm + (it & 1) * 8192;
    const F16* wbase = sm + 16384 + (it & 1) * 4096;
#pragma unroll
    for (int ks = 0; ks < 2; ++ks) {
      f16x8 af[4], bf[2];
#pragma unroll
      for (int mt = 0; mt < 4; ++mt)
        af[mt] = ldsR(abase, wm * 64 + mt * 16 + l15, ks * 4 + quad);
#pragma unroll
      for (int nt = 0; nt < 2; ++nt)
        bf[nt] = ldsR(wbase, wn * 32 + nt * 16 + l15, ks * 4 + quad);
#pragma unroll
      for (int mt = 0; mt < 4; ++mt)
#pragma unroll
        for (int nt = 0; nt < 2; ++nt)
          acc[mt][nt] = __builtin_amdgcn_mfma_f32_16x16x32_f16(af[mt], bf[nt], acc[mt][nt], 0, 0, 0);
    }
  }

#pragma unroll
  for (int nt = 0; nt < 2; ++nt) {
    int cg = colblk + wn * 32 + nt * 16 + l15;
    float bv = bias[cg];
#pragma unroll
    for (int mt = 0; mt < 4; ++mt)
#pragma unroll
      for (int i = 0; i < 4; ++i) {
        int rg = rowblk + wm * 64 + mt * 16 + quad * 4 + i;
        out[(size_t)rg * CC + cg] = acc[mt][nt][i] + bv;
      }
  }
}

// ---------------------------------------------------------------------------
// K3: MFMA flash attention, S^T form, K/V double-buffered (64 KB LDS) ->
// single barrier per 128-key iter; staging hidden behind S/softmax/PV.
// ---------------------------------------------------------------------------
__global__ __launch_bounds__(256)
void attn_mfma(const F16* __restrict__ Qh, const F16* __restrict__ Kh,
               const F16* __restrict__ Vt, F16* __restrict__ AO) {
  __shared__ alignas(16) F16 KV[2][4][4096];  // [buf][K0 K1 V0 V1]

  const int tid = threadIdx.x, lane = tid & 63, w = tid >> 6;
  const int l15 = lane & 15, quad = lane >> 4;

  const int flat = blockIdx.y * 8 + blockIdx.x;
  const int xcd = flat & 7, g = flat >> 3;
  const int bh = xcd * 12 + g % 12;
  const int q0 = (g / 12) * 128 + w * 32;

  const size_t kqbase = (size_t)bh * NN * DH;
  const size_t vbase  = (size_t)bh * DH * NN;

  const int rloc = lane >> 3, ploc = lane & 7;
  const int cK = ploc ^ rloc;

  f16x8 qf[2][2];
#pragma unroll
  for (int qn = 0; qn < 2; ++qn)
#pragma unroll
    for (int st = 0; st < 2; ++st)
      qf[qn][st] = *(const f16x8*)(Qh + kqbase +
                    (size_t)(q0 + qn * 16 + l15) * DH + st * 32 + quad * 8);

  f32x4 o[2][4];
  float m_i[2], l_i[2];
#pragma unroll
  for (int qn = 0; qn < 2; ++qn) {
    m_i[qn] = -1e30f; l_i[qn] = 0.f;
#pragma unroll
    for (int gd = 0; gd < 4; ++gd) o[qn][gd] = (f32x4){0.f, 0.f, 0.f, 0.f};
  }

  // prologue: stage kt=0 into buf 0 (wave-specialized: w<2 K, w>=2 V)
  if (w < 2) {
#pragma unroll
    for (int j = 0; j < 8; ++j)
      gld16(Kh + kqbase + (size_t)(w * 64 + 8 * j + rloc) * DH + cK * 8,
            KV[0][w] + j * 512);
  } else {
#pragma unroll
    for (int j = 0; j < 8; ++j)
      gld16(Vt + vbase + (size_t)(8 * j + rloc) * NN + (w - 2) * 64 + cK * 8,
            KV[0][w] + j * 512);
  }

#pragma unroll 1
  for (int it = 0; it < 8; ++it) {
    __syncthreads();   // drains gld16(it); buf[(it+1)&1] free for prefetch
    if (it < 7) {
      int kt2 = (it + 1) * 128;
      F16* dst = KV[(it + 1) & 1][w];
      if (w < 2) {
#pragma unroll
        for (int j = 0; j < 8; ++j)
          gld16(Kh + kqbase + (size_t)(kt2 + w * 64 + 8 * j + rloc) * DH + cK * 8,
                dst + j * 512);
      } else {
#pragma unroll
        for (int j = 0; j < 8; ++j)
          gld16(Vt + vbase + (size_t)(8 * j + rloc) * NN + kt2 + (w - 2) * 64 + cK * 8,
                dst + j * 512);
      }
    }
    const F16* Ks0 = KV[it & 1][0];
    const F16* Ks1 = KV[it & 1][1];
    const F16* Vs0 = KV[it & 1][2];
    const F16* Vs1 = KV[it & 1][3];

    // scores for all 128 keys, both qn
    f32x4 s[2][8];
#pragma unroll
    for (int grp = 0; grp < 8; ++grp) {
      const F16* kb = (grp < 4) ? Ks0 : Ks1;
      int m = (grp & 3) * 16 + l15;
      f16x8 kf0 = ldsR(kb, m, quad);
      f16x8 kf1 = ldsR(kb, m, 4 + quad);
#pragma unroll
      for (int qn = 0; qn < 2; ++qn) {
        f32x4 t = (f32x4){0.f, 0.f, 0.f, 0.f};
        t = __builtin_amdgcn_mfma_f32_16x16x32_f16(kf0, qf[qn][0], t, 0, 0, 0);
        t = __builtin_amdgcn_mfma_f32_16x16x32_f16(kf1, qf[qn][1], t, 0, 0, 0);
        s[qn][grp] = t;
      }
    }

    // one online-softmax pass per qn over 128 keys
    f16x4 pk[2][8];
#pragma unroll
    for (int qn = 0; qn < 2; ++qn) {
      float rm = -1e30f;
#pragma unroll
      for (int grp = 0; grp < 8; ++grp)
#pragma unroll
        for (int i = 0; i < 4; ++i) rm = fmaxf(rm, s[qn][grp][i]);
      rm = fmaxf(rm, __shfl_xor(rm, 16, 64));
      rm = fmaxf(rm, __shfl_xor(rm, 32, 64));
      float mn = fmaxf(m_i[qn], rm);
      float alpha = __expf(m_i[qn] - mn);
      float rs = 0.f;
#pragma unroll
      for (int grp = 0; grp < 8; ++grp)
#pragma unroll
        for (int i = 0; i < 4; ++i) {
          float p = __expf(s[qn][grp][i] - mn);
          rs += p;
          pk[qn][grp][i] = (F16)p;
        }
      rs += __shfl_xor(rs, 16, 64);
      rs += __shfl_xor(rs, 32, 64);
      l_i[qn] = l_i[qn] * alpha + rs;
      m_i[qn] = mn;
#pragma unroll
      for (int gd = 0; gd < 4; ++gd) o[qn][gd] *= alpha;
    }

    // PV: K=16 MFMA, P consumed directly in C-layout
#pragma unroll
    for (int grp = 0; grp < 8; ++grp) {
      const F16* vb = (grp < 4) ? Vs0 : Vs1;
      int c2 = ((grp & 3) << 1) + (quad >> 1);
      int off = (quad & 1) * 4;
#pragma unroll
      for (int gd = 0; gd < 4; ++gd) {
        f16x4 vf = ldsV4(vb, gd * 16 + l15, c2, off);
        o[0][gd] = __builtin_amdgcn_mfma_f32_16x16x16f16(vf, pk[0][grp], o[0][gd], 0, 0, 0);
        o[1][gd] = __builtin_amdgcn_mfma_f32_16x16x16f16(vf, pk[1][grp], o[1][gd], 0, 0, 0);
      }
    }
  }

  // epilogue
  const int b = bh / HH, h = bh % HH;
#pragma unroll
  for (int qn = 0; qn < 2; ++qn) {
    float invl = 1.0f / l_i[qn];
    int n = q0 + qn * 16 + l15;
#pragma unroll
    for (int gd = 0; gd < 4; ++gd) {
      f16x4 hv;
#pragma unroll
      for (int i = 0; i < 4; ++i) hv[i] = (F16)(o[qn][gd][i] * invl);
      size_t idx = ((size_t)(b * NN + n)) * CC + h * DH + gd * 16 + quad * 4;
      *(f16x4*)(AO + idx) = hv;
    }
  }
}

// ---------------------------------------------------------------------------
extern "C" void kernel_launch(void* const* d_in, const int* in_sizes, int n_in,
                              void* d_out, int out_size, void* d_ws, size_t ws_size,
                              hipStream_t stream) {
  const float* x      = (const float*)d_in[0];
  const float* qkv_w  = (const float*)d_in[1];
  const float* qkv_b  = (const float*)d_in[2];
  const float* proj_w = (const float*)d_in[3];
  const float* proj_b = (const float*)d_in[4];
  const int*   pos2d  = (const int*)d_in[5];
  const int num_img = in_sizes[5] / (2 * BB);

  char* ws = (char*)d_ws;
  F16* wq_h = (F16*)(ws + 0);             // 3,538,944 B
  F16* wp_h = (F16*)(ws + 3538944);       // 1,179,648 B
  F16* q_h  = (F16*)(ws + 4718592);       // 12,582,912 B each
  F16* k_h  = (F16*)(ws + 17301504);
  F16* vt   = (F16*)(ws + 29884416);      // V transposed [b,h,d,n]
  F16* ao_h = (F16*)(ws + 42467328);      // end 55,050,240 B
  float* out = (float*)d_out;

  convert_w<<<(NW1 + NW2 + 255) / 256, 256, 0, stream>>>(qkv_w, proj_w, wq_h, wp_h);

  gemm_qkv_rope<<<dim3(QKV3 / 128, (BB * NN) / 128), 256, 0, stream>>>(
      x, wq_h, qkv_b, pos2d, q_h, k_h, vt, num_img);

  attn_mfma<<<dim3(NN / 128, BB * HH), 256, 0, stream>>>(
      q_h, k_h, vt, ao_h);

  gemm_proj<<<dim3(CC / 64, (BB * NN) / 128), 256, 0, stream>>>(
      ao_h, wp_h, proj_b, out);
}